// Round 7
// baseline (544.668 us; speedup 1.0000x reference)
//
#include <hip/hip_runtime.h>
#include <hip/hip_bf16.h>

#define N_NODES 100000
#define N_EDGES 1200000
#define N_GRAPHS 512
#define HID 64
#define IN_DIM 16
#define EPS 1e-5f

#define NB_BUCKETS 391   // ceil(N_NODES / BUCKET_SPAN)
#define BUCKET_SPAN 256  // dst >> 8
#define REGION 4096      // per-bucket region capacity (avg real fill ~3069)
#define BIN_TILE 4096    // edges per bin block
#define CSR_LEN (N_EDGES + N_NODES)  // self-loops folded in

// ---------------- CSR build (bucketed, LDS-built, self-loops included) ----------------

__global__ void bin_kernel(const int* __restrict__ ei, int* __restrict__ bucketCnt,
                           int* __restrict__ regions) {
    __shared__ int hist[NB_BUCKETS], basem[NB_BUCKETS], cur[NB_BUCKETS];
    int t = threadIdx.x;
    for (int i = t; i < NB_BUCKETS; i += 256) { hist[i] = 0; cur[i] = 0; }
    __syncthreads();
    int e0 = blockIdx.x * BIN_TILE;
    int srcs[16], dsts[16];
#pragma unroll
    for (int i = 0; i < 16; i++) {
        int e = e0 + t + i * 256;
        if (e < N_EDGES) {
            srcs[i] = ei[e];
            dsts[i] = ei[N_EDGES + e];
            atomicAdd(&hist[dsts[i] >> 8], 1);
        } else {
            dsts[i] = -1;
        }
    }
    __syncthreads();
    for (int i = t; i < NB_BUCKETS; i += 256) {
        int h = hist[i];
        basem[i] = h ? atomicAdd(&bucketCnt[i], h) : 0;
    }
    __syncthreads();
#pragma unroll
    for (int i = 0; i < 16; i++) {
        if (dsts[i] >= 0) {
            int b = dsts[i] >> 8;
            int pos = basem[b] + atomicAdd(&cur[b], 1);
            if (pos < REGION)
                regions[b * REGION + pos] = srcs[i] | ((dsts[i] & 255) << 17);
        }
    }
}

__global__ void build_kernel(const int* __restrict__ regions, const int* __restrict__ bucketCnt,
                             int* __restrict__ csrOff, int* __restrict__ csrSrc,
                             float* __restrict__ dis) {
    __shared__ int deg[256], off[256], cur[256];
    __shared__ int slice[REGION + 256];
    __shared__ int sTot, sBase;
    int b = blockIdx.x, t = threadIdx.x;
    {
        int s = 0;
        for (int i = t; i < NB_BUCKETS; i += 256)
            if (i < b) s += min(bucketCnt[i], REGION);
        deg[t] = s;
        __syncthreads();
        for (int k = 128; k > 0; k >>= 1) {
            if (t < k) deg[t] += deg[t + k];
            __syncthreads();
        }
        if (t == 0) sBase = deg[0] + b * BUCKET_SPAN;
        __syncthreads();
    }
    int bb = sBase;
    int cnt = min(bucketCnt[b], REGION);
    int nbase = b * BUCKET_SPAN;
    int n = nbase + t;
    bool valid = (n < N_NODES);
    deg[t] = valid ? 1 : 0;  // self loop
    __syncthreads();
    for (int i = t; i < cnt; i += 256) {
        int rec = regions[b * REGION + i];
        atomicAdd(&deg[rec >> 17], 1);
    }
    __syncthreads();
    int d = deg[t];
    off[t] = d;
    __syncthreads();
    for (int s = 1; s < 256; s <<= 1) {
        int v = (t >= s) ? off[t - s] : 0;
        __syncthreads();
        off[t] += v;
        __syncthreads();
    }
    int excl = off[t] - d;
    if (valid) {
        csrOff[n] = bb + excl;
        dis[n] = rsqrtf((float)d);
    }
    if (b == 0 && t == 0) csrOff[N_NODES] = CSR_LEN;
    if (t == 255) sTot = off[255];
    cur[t] = excl;
    __syncthreads();
    if (valid) {
        int pos = atomicAdd(&cur[t], 1);
        slice[pos] = n;
    }
    for (int i = t; i < cnt; i += 256) {
        int rec = regions[b * REGION + i];
        int pos = atomicAdd(&cur[rec >> 17], 1);
        slice[pos] = rec & 0x1FFFF;
    }
    __syncthreads();
    int tot = sTot;
    for (int i = t; i < tot; i += 256) csrSrc[bb + i] = slice[i];
}

// ---------------- BN statistics over x (also zeroes hwBuf dummy row) ----------------

__global__ void stats_x(const float* __restrict__ x, float* __restrict__ sums,
                        float* __restrict__ sumsq, float* __restrict__ hwBuf) {
    __shared__ float ls[16], lq[16];
    int t = threadIdx.x;
    if (blockIdx.x == 0 && t < 16)
        ((float4*)(hwBuf + (size_t)N_NODES * HID))[t] = make_float4(0.f, 0.f, 0.f, 0.f);
    if (t < 16) { ls[t] = 0.f; lq[t] = 0.f; }
    __syncthreads();
    float s = 0.f, q = 0.f;
    const int total = N_NODES * IN_DIM;
    for (int i = blockIdx.x * blockDim.x + t; i < total; i += gridDim.x * blockDim.x) {
        float v = x[i];
        s += v; q += v * v;
    }
    int k = t & 15;
    atomicAdd(&ls[k], s);
    atomicAdd(&lq[k], q);
    __syncthreads();
    if (t < 16) { atomicAdd(&sums[t], ls[t]); atomicAdd(&sumsq[t], lq[t]); }
}

__device__ __forceinline__ void bn_coef(const float* sums, const float* sumsq,
                                        const float* gamma, const float* beta, int k,
                                        float& sc, float& sh) {
    const float invn = 1.0f / (float)N_NODES;
    float m = sums[k] * invn;
    float var = sumsq[k] * invn - m * m;
    float rs = rsqrtf(var + EPS);
    sc = gamma[k] * rs;
    sh = beta[k] - m * sc;
}

// ---------------- Layer 0: pre-aggregation path ----------------

// m[n] = BN(x[n]) * dis[n]  (16 floats/row); zeroes dummy row N_NODES
__global__ void premsg_kernel(const float* __restrict__ x, const float* __restrict__ sums,
                              const float* __restrict__ sumsq, const float* __restrict__ gamma,
                              const float* __restrict__ beta, const float* __restrict__ dis,
                              float4* __restrict__ m4) {
    __shared__ float sc16[16], sh16[16];
    int t = threadIdx.x;
    if (t < 16) bn_coef(sums, sumsq, gamma, beta, t, sc16[t], sh16[t]);
    __syncthreads();
    int idx = blockIdx.x * 256 + t;  // float4 index
    if (idx < (N_NODES + 1) * 4) {
        int n = idx >> 2, c = idx & 3;
        float4 v = make_float4(0.f, 0.f, 0.f, 0.f);
        if (n < N_NODES) {
            float4 h = ((const float4*)x)[idx];
            float d = dis[n];
            v.x = (h.x * sc16[c * 4 + 0] + sh16[c * 4 + 0]) * d;
            v.y = (h.y * sc16[c * 4 + 1] + sh16[c * 4 + 1]) * d;
            v.z = (h.z * sc16[c * 4 + 2] + sh16[c * 4 + 2]) * d;
            v.w = (h.w * sc16[c * 4 + 3] + sh16[c * 4 + 3]) * d;
        }
        m4[idx] = v;
    }
}

// agg[i] = dis[i] * sum_{j in N(i)} m[j]   (16 floats/row; 16 edge slots x float4)
__global__ void aggregate16_kernel(const float4* __restrict__ m4, const int* __restrict__ csrOff,
                                   const int* __restrict__ csrSrc, const float* __restrict__ dis,
                                   float4* __restrict__ agg4) {
    const int lane = threadIdx.x & 63;
    const int wid = threadIdx.x >> 6;
    const int q = lane >> 2;   // edge slot 0..15
    const int fl = lane & 3;   // float4 column (row = 4 float4s)
    const int wave = blockIdx.x * 4 + wid;
    const int nwaves = gridDim.x * 4;

    for (int n = wave; n < N_NODES; n += nwaves) {
        int beg = csrOff[n], end = csrOff[n + 1];
        float4 acc = make_float4(0.f, 0.f, 0.f, 0.f);
        int e = beg + q;
        int i0 = (e < end) ? csrSrc[e] : N_NODES;
        int i1 = (e + 16 < end) ? csrSrc[e + 16] : N_NODES;
        while (e < end) {
            int j0 = i0, j1 = i1;
            e += 32;
            i0 = (e < end) ? csrSrc[e] : N_NODES;
            i1 = (e + 16 < end) ? csrSrc[e + 16] : N_NODES;
            float4 v0 = m4[(size_t)j0 * 4 + fl];
            float4 v1 = m4[(size_t)j1 * 4 + fl];
            acc.x += v0.x + v1.x; acc.y += v0.y + v1.y;
            acc.z += v0.z + v1.z; acc.w += v0.w + v1.w;
        }
        acc.x += __shfl_xor(acc.x, 4, 64);
        acc.y += __shfl_xor(acc.y, 4, 64);
        acc.z += __shfl_xor(acc.z, 4, 64);
        acc.w += __shfl_xor(acc.w, 4, 64);
        acc.x += __shfl_xor(acc.x, 8, 64);
        acc.y += __shfl_xor(acc.y, 8, 64);
        acc.z += __shfl_xor(acc.z, 8, 64);
        acc.w += __shfl_xor(acc.w, 8, 64);
        acc.x += __shfl_xor(acc.x, 16, 64);
        acc.y += __shfl_xor(acc.y, 16, 64);
        acc.z += __shfl_xor(acc.z, 16, 64);
        acc.w += __shfl_xor(acc.w, 16, 64);
        acc.x += __shfl_xor(acc.x, 32, 64);
        acc.y += __shfl_xor(acc.y, 32, 64);
        acc.z += __shfl_xor(acc.z, 32, 64);
        acc.w += __shfl_xor(acc.w, 32, 64);
        if (q == 0) {
            float d = dis[n];
            acc.x *= d; acc.y *= d; acc.z *= d; acc.w *= d;
            agg4[(size_t)n * 4 + fl] = acc;
        }
    }
}

// y = agg @ W0 + b0 ; accumulate BN stats of y
#define G16P_ROWS 64
__global__ void gemm16p_kernel(const float* __restrict__ agg, const float* __restrict__ W,
                               const float* __restrict__ bias, float* __restrict__ y,
                               float* __restrict__ sums, float* __restrict__ sumsq) {
    __shared__ float Ws[IN_DIM][HID];
    __shared__ float xs[G16P_ROWS][IN_DIM + 1];
    __shared__ float ls[4][64], lq[4][64];
    int t = threadIdx.x, f = t & 63, nl = t >> 6;
    for (int i = t; i < IN_DIM * HID; i += 256) Ws[i >> 6][i & 63] = W[i];
    int base = blockIdx.x * G16P_ROWS;
    for (int i = t; i < G16P_ROWS * IN_DIM; i += 256) {
        int r = i >> 4, k = i & 15;
        int n = base + r;
        xs[r][k] = (n < N_NODES) ? agg[n * IN_DIM + k] : 0.f;
    }
    __syncthreads();
    float b = bias[f];
    float acc[16];
#pragma unroll
    for (int r = 0; r < 16; r++) acc[r] = 0.f;
    for (int k = 0; k < IN_DIM; k++) {
        float wk = Ws[k][f];
#pragma unroll
        for (int r = 0; r < 16; r++) acc[r] += xs[nl * 16 + r][k] * wk;
    }
    float sv = 0.f, qv = 0.f;
#pragma unroll
    for (int r = 0; r < 16; r++) {
        int n = base + nl * 16 + r;
        if (n < N_NODES) {
            float val = acc[r] + b;
            y[n * HID + f] = val;
            sv += val;
            qv += val * val;
        }
    }
    ls[nl][f] = sv;
    lq[nl][f] = qv;
    __syncthreads();
    if (nl == 0) {
        float S = ls[0][f] + ls[1][f] + ls[2][f] + ls[3][f];
        float Q = lq[0][f] + lq[1][f] + lq[2][f] + lq[3][f];
        atomicAdd(&sums[f], S);
        atomicAdd(&sumsq[f], Q);
    }
}

// ---------------- GEMM 64x64 (BN finalize + relu fused on input) ----------------

#define G64_ROWS 128
__global__ void gemm64_kernel(const float* __restrict__ hin, const float* __restrict__ W,
                              const float* __restrict__ sums, const float* __restrict__ sumsq,
                              const float* __restrict__ gamma, const float* __restrict__ beta,
                              const float* __restrict__ dis, float* __restrict__ hout) {
    __shared__ float Ws[HID * HID];          // [k][f], f contiguous
    __shared__ float hs[G64_ROWS][HID + 1];  // +1 pad
    __shared__ float scb[64], shb[64];
    int t = threadIdx.x;
    int fg = t & 15;
    int rg = t >> 4;
    int base = blockIdx.x * G64_ROWS;

    if (t < 64) bn_coef(sums, sumsq, gamma, beta, t, scb[t], shb[t]);
    {
        const float4* W4 = (const float4*)W;
        float4* Ws4 = (float4*)Ws;
        for (int i = t; i < HID * HID / 4; i += 256) Ws4[i] = W4[i];
    }
    __syncthreads();
    {
        const float4* hin4 = (const float4*)hin;
        for (int i = t; i < G64_ROWS * 16; i += 256) {
            int r = i >> 4, c = i & 15;
            int n = base + r;
            float4 v = make_float4(0.f, 0.f, 0.f, 0.f);
            if (n < N_NODES) {
                float4 h = hin4[n * 16 + c];
                v.x = fmaxf(h.x * scb[c * 4 + 0] + shb[c * 4 + 0], 0.f);
                v.y = fmaxf(h.y * scb[c * 4 + 1] + shb[c * 4 + 1], 0.f);
                v.z = fmaxf(h.z * scb[c * 4 + 2] + shb[c * 4 + 2], 0.f);
                v.w = fmaxf(h.w * scb[c * 4 + 3] + shb[c * 4 + 3], 0.f);
            }
            hs[r][c * 4 + 0] = v.x;
            hs[r][c * 4 + 1] = v.y;
            hs[r][c * 4 + 2] = v.z;
            hs[r][c * 4 + 3] = v.w;
        }
    }
    __syncthreads();

    float4 acc[8];
#pragma unroll
    for (int r = 0; r < 8; r++) acc[r] = make_float4(0.f, 0.f, 0.f, 0.f);
    const float4* Ws4 = (const float4*)Ws;
    for (int k = 0; k < HID; k++) {
        float4 wk = Ws4[k * 16 + fg];
#pragma unroll
        for (int r = 0; r < 8; r++) {
            float h = hs[rg * 8 + r][k];
            acc[r].x += h * wk.x;
            acc[r].y += h * wk.y;
            acc[r].z += h * wk.z;
            acc[r].w += h * wk.w;
        }
    }
    float4* hout4 = (float4*)hout;
#pragma unroll
    for (int r = 0; r < 8; r++) {
        int n = base + rg * 8 + r;
        if (n < N_NODES) {
            float dsc = dis[n];
            float4 o = acc[r];
            o.x *= dsc; o.y *= dsc; o.z *= dsc; o.w *= dsc;
            hout4[n * 16 + fg] = o;
        }
    }
}

// ---------------- Aggregation 64-dim (layers 1-2): pair-interleaved f32 ----------------

__global__ void aggregate_kernel(const float4* __restrict__ hw4, const int* __restrict__ csrOff,
                                 const int* __restrict__ csrSrc, const float* __restrict__ dis,
                                 const float* __restrict__ bias, float4* __restrict__ y4,
                                 float* __restrict__ sums, float* __restrict__ sumsq) {
    const int lane = threadIdx.x & 63;
    const int wid = threadIdx.x >> 6;
    const int q = lane >> 4;   // edge slot 0..3
    const int fl = lane & 15;  // float4 column
    const int wave = blockIdx.x * 4 + wid;
    const int nwaves = gridDim.x * 4;

    const float4 bias4 = ((const float4*)bias)[fl];
    float4 s_acc = make_float4(0.f, 0.f, 0.f, 0.f);
    float4 q_acc = make_float4(0.f, 0.f, 0.f, 0.f);

    for (int nA = wave; nA < N_NODES; nA += 2 * nwaves) {
        int nB = nA + nwaves;
        bool hasB = (nB < N_NODES);
        int begA = csrOff[nA], endA = csrOff[nA + 1];
        int begB = 0, endB = 0;
        if (hasB) { begB = csrOff[nB]; endB = csrOff[nB + 1]; }
        float4 accA = make_float4(0.f, 0.f, 0.f, 0.f);
        float4 accB = make_float4(0.f, 0.f, 0.f, 0.f);
        int eA = begA + q, eB = begB + q;
        int iA0 = (eA < endA) ? csrSrc[eA] : N_NODES;
        int iA1 = (eA + 4 < endA) ? csrSrc[eA + 4] : N_NODES;
        int iB0 = (eB < endB) ? csrSrc[eB] : N_NODES;
        int iB1 = (eB + 4 < endB) ? csrSrc[eB + 4] : N_NODES;
        while (eA < endA || eB < endB) {
            int jA0 = iA0, jA1 = iA1, jB0 = iB0, jB1 = iB1;
            eA += 8; eB += 8;
            iA0 = (eA < endA) ? csrSrc[eA] : N_NODES;
            iA1 = (eA + 4 < endA) ? csrSrc[eA + 4] : N_NODES;
            iB0 = (eB < endB) ? csrSrc[eB] : N_NODES;
            iB1 = (eB + 4 < endB) ? csrSrc[eB + 4] : N_NODES;
            float4 vA0 = hw4[(size_t)jA0 * 16 + fl];
            float4 vA1 = hw4[(size_t)jA1 * 16 + fl];
            float4 vB0 = hw4[(size_t)jB0 * 16 + fl];
            float4 vB1 = hw4[(size_t)jB1 * 16 + fl];
            accA.x += vA0.x + vA1.x; accA.y += vA0.y + vA1.y;
            accA.z += vA0.z + vA1.z; accA.w += vA0.w + vA1.w;
            accB.x += vB0.x + vB1.x; accB.y += vB0.y + vB1.y;
            accB.z += vB0.z + vB1.z; accB.w += vB0.w + vB1.w;
        }
        accA.x += __shfl_xor(accA.x, 16, 64);
        accA.y += __shfl_xor(accA.y, 16, 64);
        accA.z += __shfl_xor(accA.z, 16, 64);
        accA.w += __shfl_xor(accA.w, 16, 64);
        accA.x += __shfl_xor(accA.x, 32, 64);
        accA.y += __shfl_xor(accA.y, 32, 64);
        accA.z += __shfl_xor(accA.z, 32, 64);
        accA.w += __shfl_xor(accA.w, 32, 64);
        accB.x += __shfl_xor(accB.x, 16, 64);
        accB.y += __shfl_xor(accB.y, 16, 64);
        accB.z += __shfl_xor(accB.z, 16, 64);
        accB.w += __shfl_xor(accB.w, 16, 64);
        accB.x += __shfl_xor(accB.x, 32, 64);
        accB.y += __shfl_xor(accB.y, 32, 64);
        accB.z += __shfl_xor(accB.z, 32, 64);
        accB.w += __shfl_xor(accB.w, 32, 64);
        if (q == 0) {
            float dA = dis[nA];
            float4 valA;
            valA.x = accA.x * dA + bias4.x;
            valA.y = accA.y * dA + bias4.y;
            valA.z = accA.z * dA + bias4.z;
            valA.w = accA.w * dA + bias4.w;
            y4[(size_t)nA * 16 + fl] = valA;
            s_acc.x += valA.x; s_acc.y += valA.y; s_acc.z += valA.z; s_acc.w += valA.w;
            q_acc.x += valA.x * valA.x; q_acc.y += valA.y * valA.y;
            q_acc.z += valA.z * valA.z; q_acc.w += valA.w * valA.w;
            if (hasB) {
                float dB = dis[nB];
                float4 valB;
                valB.x = accB.x * dB + bias4.x;
                valB.y = accB.y * dB + bias4.y;
                valB.z = accB.z * dB + bias4.z;
                valB.w = accB.w * dB + bias4.w;
                y4[(size_t)nB * 16 + fl] = valB;
                s_acc.x += valB.x; s_acc.y += valB.y; s_acc.z += valB.z; s_acc.w += valB.w;
                q_acc.x += valB.x * valB.x; q_acc.y += valB.y * valB.y;
                q_acc.z += valB.z * valB.z; q_acc.w += valB.w * valB.w;
            }
        }
    }
    __shared__ float ls[4][64], lq[4][64];
    ls[wid][lane] = 0.f;
    lq[wid][lane] = 0.f;
    if (q == 0) {
        ls[wid][fl * 4 + 0] = s_acc.x; ls[wid][fl * 4 + 1] = s_acc.y;
        ls[wid][fl * 4 + 2] = s_acc.z; ls[wid][fl * 4 + 3] = s_acc.w;
        lq[wid][fl * 4 + 0] = q_acc.x; lq[wid][fl * 4 + 1] = q_acc.y;
        lq[wid][fl * 4 + 2] = q_acc.z; lq[wid][fl * 4 + 3] = q_acc.w;
    }
    __syncthreads();
    if (wid == 0) {
        float S = ls[0][lane] + ls[1][lane] + ls[2][lane] + ls[3][lane];
        float Q = lq[0][lane] + lq[1][lane] + lq[2][lane] + lq[3][lane];
        atomicAdd(&sums[lane], S);
        atomicAdd(&sumsq[lane], Q);
    }
}

// ---------------- Pool (BN finalize fused) + head ----------------

#define POOL_CHUNK 256
__global__ void pool_kernel(const float* __restrict__ y, const int* __restrict__ batch,
                            const float* __restrict__ sums, const float* __restrict__ sumsq,
                            const float* __restrict__ gamma, const float* __restrict__ beta,
                            float* __restrict__ pool, float* __restrict__ cnt) {
    int f = threadIdx.x & 63;
    int nl = threadIdx.x >> 6;
    float sc, sh;
    bn_coef(sums, sumsq, gamma, beta, f, sc, sh);
    int base = blockIdx.x * POOL_CHUNK;
    int endn = min(base + POOL_CHUNK, N_NODES);
    int g_cur = -1;
    float acc = 0.f;
    float c_acc = 0.f;
    for (int n = base + nl; n < endn; n += 4) {
        int g = batch[n];
        float v = fmaxf(y[n * HID + f] * sc + sh, 0.f);
        if (g != g_cur) {
            if (g_cur >= 0) {
                atomicAdd(&pool[g_cur * HID + f], acc);
                if (f == 0) atomicAdd(&cnt[g_cur], c_acc);
            }
            g_cur = g;
            acc = 0.f;
            c_acc = 0.f;
        }
        acc += v;
        c_acc += 1.f;
    }
    if (g_cur >= 0) {
        atomicAdd(&pool[g_cur * HID + f], acc);
        if (f == 0) atomicAdd(&cnt[g_cur], c_acc);
    }
}

__global__ void head_kernel(const float* __restrict__ pool, const float* __restrict__ cnt,
                            const float* __restrict__ Wc1, const float* __restrict__ bc1,
                            const float* __restrict__ Wc2, const float* __restrict__ bc2,
                            float* __restrict__ out) {
    int g = blockIdx.x;
    int f = threadIdx.x;  // 64 threads
    __shared__ float p[64], z[64];
    float c = fmaxf(cnt[g], 1.0f);
    p[f] = pool[g * HID + f] / c;
    __syncthreads();
    float acc = bc1[f];
    for (int k = 0; k < 64; k++) acc += p[k] * Wc1[k * 64 + f];
    z[f] = fmaxf(acc, 0.f);
    __syncthreads();
    if (f < 2) {
        float o = bc2[f];
        for (int k = 0; k < 64; k++) o += z[k] * Wc2[k * 2 + f];
        out[g * 2 + f] = o;
    }
}

// ---------------- launch ----------------

extern "C" void kernel_launch(void* const* d_in, const int* in_sizes, int n_in,
                              void* d_out, int out_size, void* d_ws, size_t ws_size,
                              hipStream_t stream) {
    const float* x      = (const float*)d_in[0];
    const int*   ei     = (const int*)d_in[1];
    const int*   batch  = (const int*)d_in[2];
    const float* bn_in_g = (const float*)d_in[3];
    const float* bn_in_b = (const float*)d_in[4];
    const float* W0 = (const float*)d_in[5];
    const float* b0 = (const float*)d_in[6];
    const float* g0 = (const float*)d_in[7];
    const float* be0 = (const float*)d_in[8];
    const float* W1 = (const float*)d_in[9];
    const float* b1 = (const float*)d_in[10];
    const float* g1 = (const float*)d_in[11];
    const float* be1 = (const float*)d_in[12];
    const float* W2 = (const float*)d_in[13];
    const float* b2 = (const float*)d_in[14];
    const float* g2 = (const float*)d_in[15];
    const float* be2 = (const float*)d_in[16];
    const float* Wc1 = (const float*)d_in[17];
    const float* bc1 = (const float*)d_in[18];
    const float* Wc2 = (const float*)d_in[19];
    const float* bc2 = (const float*)d_in[20];
    float* out = (float*)d_out;

    char* w = (char*)d_ws;
    size_t off = 0;
    auto take = [&](size_t bytes) {
        size_t r = off;
        off += (bytes + 255) & ~(size_t)255;
        return r;
    };
    // ---- zero region (one memset) ----
    float* stats  = (float*)(w + take(4 * 256 * 4));  // slot l: [sums 64][sumsq 64]
    float* pool   = (float*)(w + take((size_t)N_GRAPHS * HID * 4));
    float* cnt    = (float*)(w + take((size_t)N_GRAPHS * 4));
    int* bucketCnt = (int*)(w + take((size_t)NB_BUCKETS * 4));
    size_t zero_end = off;
    // ---- rest ----
    float* dis    = (float*)(w + take((size_t)N_NODES * 4));
    int* csrOff   = (int*)(w + take((size_t)(N_NODES + 1) * 4));
    int* csrSrc   = (int*)(w + take((size_t)(CSR_LEN + 64) * 4));
    float* hwBuf  = (float*)(w + take((size_t)(N_NODES + 1) * HID * 4));  // +dummy zero row
    float* yBuf   = (float*)(w + take((size_t)N_NODES * HID * 4));
    float* aggBuf = (float*)(w + take((size_t)N_NODES * IN_DIM * 4));
    int* regions  = (int*)hwBuf;   // alias: consumed by build_kernel before premsg
    float* msgBuf = (float*)hwBuf; // alias: m[(N+1),16] consumed by aggregate16 before gemm64
    (void)ws_size; (void)n_in; (void)in_sizes; (void)out_size;

    hipMemsetAsync(w, 0, zero_end, stream);

    const int nbBin  = (N_EDGES + BIN_TILE - 1) / BIN_TILE;  // 293
    const int nbPre  = ((N_NODES + 1) * 4 + 255) / 256;
    const int nbG16p = (N_NODES + G16P_ROWS - 1) / G16P_ROWS;
    const int nbG64  = (N_NODES + G64_ROWS - 1) / G64_ROWS;
    const int nbAgg  = 2048;

    // CSR build (bucketed; self-loops folded in)
    bin_kernel<<<nbBin, 256, 0, stream>>>(ei, bucketCnt, regions);
    build_kernel<<<NB_BUCKETS, 256, 0, stream>>>(regions, bucketCnt, csrOff, csrSrc, dis);

    float* s0 = stats + 0 * 256;
    float* s1 = stats + 1 * 256;
    float* s2 = stats + 2 * 256;
    float* s3 = stats + 3 * 256;

    // input BN stats (also zeroes hwBuf dummy row)
    stats_x<<<256, 256, 0, stream>>>(x, s0, s0 + 64, hwBuf);

    // layer 0: pre-aggregate 16-dim, then GEMM
    premsg_kernel<<<nbPre, 256, 0, stream>>>(x, s0, s0 + 64, bn_in_g, bn_in_b, dis,
                                             (float4*)msgBuf);
    aggregate16_kernel<<<nbAgg, 256, 0, stream>>>((const float4*)msgBuf, csrOff, csrSrc, dis,
                                                  (float4*)aggBuf);
    gemm16p_kernel<<<nbG16p, 256, 0, stream>>>(aggBuf, W0, b0, yBuf, s1, s1 + 64);

    // layer 1
    gemm64_kernel<<<nbG64, 256, 0, stream>>>(yBuf, W1, s1, s1 + 64, g0, be0, dis, hwBuf);
    aggregate_kernel<<<nbAgg, 256, 0, stream>>>((const float4*)hwBuf, csrOff, csrSrc, dis, b1,
                                                (float4*)yBuf, s2, s2 + 64);
    // layer 2
    gemm64_kernel<<<nbG64, 256, 0, stream>>>(yBuf, W2, s2, s2 + 64, g1, be1, dis, hwBuf);
    aggregate_kernel<<<nbAgg, 256, 0, stream>>>((const float4*)hwBuf, csrOff, csrSrc, dis, b2,
                                                (float4*)yBuf, s3, s3 + 64);

    // pool + head
    const int nbPool = (N_NODES + POOL_CHUNK - 1) / POOL_CHUNK;
    pool_kernel<<<nbPool, 256, 0, stream>>>(yBuf, batch, s3, s3 + 64, g2, be2, pool, cnt);
    head_kernel<<<N_GRAPHS, 64, 0, stream>>>(pool, cnt, Wc1, bc1, Wc2, bc2, out);
}

// Round 8
// 459.855 us; speedup vs baseline: 1.1844x; 1.1844x over previous
//
#include <hip/hip_runtime.h>
#include <hip/hip_bf16.h>

#define N_NODES 100000
#define N_EDGES 1200000
#define N_GRAPHS 512
#define HID 64
#define IN_DIM 16
#define EPS 1e-5f

#define NB_BUCKETS 391   // ceil(N_NODES / BUCKET_SPAN)
#define BUCKET_SPAN 256  // dst >> 8
#define REGION 4096      // per-bucket region capacity (avg real fill ~3069)
#define BIN_TILE 4096    // edges per bin block
#define CSR_LEN (N_EDGES + N_NODES)  // self-loops folded in
#define NREP 64          // stats replicas (atomic de-contention)

// ---------------- CSR build (bucketed, LDS-built, self-loops included) ----------------

__global__ void bin_kernel(const int* __restrict__ ei, int* __restrict__ bucketCnt,
                           int* __restrict__ regions) {
    __shared__ int hist[NB_BUCKETS], basem[NB_BUCKETS], cur[NB_BUCKETS];
    int t = threadIdx.x;
    for (int i = t; i < NB_BUCKETS; i += 256) { hist[i] = 0; cur[i] = 0; }
    __syncthreads();
    int e0 = blockIdx.x * BIN_TILE;
    int srcs[16], dsts[16];
#pragma unroll
    for (int i = 0; i < 16; i++) {
        int e = e0 + t + i * 256;
        if (e < N_EDGES) {
            srcs[i] = ei[e];
            dsts[i] = ei[N_EDGES + e];
            atomicAdd(&hist[dsts[i] >> 8], 1);
        } else {
            dsts[i] = -1;
        }
    }
    __syncthreads();
    for (int i = t; i < NB_BUCKETS; i += 256) {
        int h = hist[i];
        basem[i] = h ? atomicAdd(&bucketCnt[i], h) : 0;
    }
    __syncthreads();
#pragma unroll
    for (int i = 0; i < 16; i++) {
        if (dsts[i] >= 0) {
            int b = dsts[i] >> 8;
            int pos = basem[b] + atomicAdd(&cur[b], 1);
            if (pos < REGION)
                regions[b * REGION + pos] = srcs[i] | ((dsts[i] & 255) << 17);
        }
    }
}

__global__ void build_kernel(const int* __restrict__ regions, const int* __restrict__ bucketCnt,
                             int* __restrict__ csrOff, int* __restrict__ csrSrc,
                             float* __restrict__ dis) {
    __shared__ int deg[256], off[256], cur[256];
    __shared__ int slice[REGION + 256];
    __shared__ int sTot, sBase;
    int b = blockIdx.x, t = threadIdx.x;
    {
        int s = 0;
        for (int i = t; i < NB_BUCKETS; i += 256)
            if (i < b) s += min(bucketCnt[i], REGION);
        deg[t] = s;
        __syncthreads();
        for (int k = 128; k > 0; k >>= 1) {
            if (t < k) deg[t] += deg[t + k];
            __syncthreads();
        }
        if (t == 0) sBase = deg[0] + b * BUCKET_SPAN;
        __syncthreads();
    }
    int bb = sBase;
    int cnt = min(bucketCnt[b], REGION);
    int nbase = b * BUCKET_SPAN;
    int n = nbase + t;
    bool valid = (n < N_NODES);
    deg[t] = valid ? 1 : 0;  // self loop
    __syncthreads();
    for (int i = t; i < cnt; i += 256) {
        int rec = regions[b * REGION + i];
        atomicAdd(&deg[rec >> 17], 1);
    }
    __syncthreads();
    int d = deg[t];
    off[t] = d;
    __syncthreads();
    for (int s = 1; s < 256; s <<= 1) {
        int v = (t >= s) ? off[t - s] : 0;
        __syncthreads();
        off[t] += v;
        __syncthreads();
    }
    int excl = off[t] - d;
    if (valid) {
        csrOff[n] = bb + excl;
        dis[n] = rsqrtf((float)d);
    }
    if (b == 0 && t == 0) csrOff[N_NODES] = CSR_LEN;
    if (t == 255) sTot = off[255];
    cur[t] = excl;
    __syncthreads();
    if (valid) {
        int pos = atomicAdd(&cur[t], 1);
        slice[pos] = n;
    }
    for (int i = t; i < cnt; i += 256) {
        int rec = regions[b * REGION + i];
        int pos = atomicAdd(&cur[rec >> 17], 1);
        slice[pos] = rec & 0x1FFFF;
    }
    __syncthreads();
    int tot = sTot;
    for (int i = t; i < tot; i += 256) csrSrc[bb + i] = slice[i];
}

// ---------------- BN statistics over x (also zeroes hwBuf dummy row) ----------------

__global__ void stats_x(const float* __restrict__ x, float* __restrict__ sums,
                        float* __restrict__ sumsq, float* __restrict__ hwBuf) {
    __shared__ float ls[16], lq[16];
    int t = threadIdx.x;
    if (blockIdx.x == 0 && t < 16)
        ((float4*)(hwBuf + (size_t)N_NODES * HID))[t] = make_float4(0.f, 0.f, 0.f, 0.f);
    if (t < 16) { ls[t] = 0.f; lq[t] = 0.f; }
    __syncthreads();
    float s = 0.f, q = 0.f;
    const int total = N_NODES * IN_DIM;
    for (int i = blockIdx.x * blockDim.x + t; i < total; i += gridDim.x * blockDim.x) {
        float v = x[i];
        s += v; q += v * v;
    }
    int k = t & 15;
    atomicAdd(&ls[k], s);
    atomicAdd(&lq[k], q);
    __syncthreads();
    if (t < 16) { atomicAdd(&sums[t], ls[t]); atomicAdd(&sumsq[t], lq[t]); }
}

__device__ __forceinline__ void bn_coef(const float* sums, const float* sumsq,
                                        const float* gamma, const float* beta, int k,
                                        float& sc, float& sh) {
    const float invn = 1.0f / (float)N_NODES;
    float m = sums[k] * invn;
    float var = sumsq[k] * invn - m * m;
    float rs = rsqrtf(var + EPS);
    sc = gamma[k] * rs;
    sh = beta[k] - m * sc;
}

// fold NREP stats replicas ([NREP][128]) into canonical [sums 64 | sumsq 64]
__global__ void reduce_stats(const float* __restrict__ rep, float* __restrict__ outStats) {
    int j = threadIdx.x;  // 0..127
    float s = 0.f;
    for (int r = 0; r < NREP; r++) s += rep[r * 128 + j];
    outStats[j] = s;
}

// ---------------- Layer 0: pre-aggregation path ----------------

// m[n] = BN(x[n]) * dis[n]  (16 floats/row); zeroes dummy row N_NODES
__global__ void premsg_kernel(const float* __restrict__ x, const float* __restrict__ sums,
                              const float* __restrict__ sumsq, const float* __restrict__ gamma,
                              const float* __restrict__ beta, const float* __restrict__ dis,
                              float4* __restrict__ m4) {
    __shared__ float sc16[16], sh16[16];
    int t = threadIdx.x;
    if (t < 16) bn_coef(sums, sumsq, gamma, beta, t, sc16[t], sh16[t]);
    __syncthreads();
    int idx = blockIdx.x * 256 + t;  // float4 index
    if (idx < (N_NODES + 1) * 4) {
        int n = idx >> 2, c = idx & 3;
        float4 v = make_float4(0.f, 0.f, 0.f, 0.f);
        if (n < N_NODES) {
            float4 h = ((const float4*)x)[idx];
            float d = dis[n];
            v.x = (h.x * sc16[c * 4 + 0] + sh16[c * 4 + 0]) * d;
            v.y = (h.y * sc16[c * 4 + 1] + sh16[c * 4 + 1]) * d;
            v.z = (h.z * sc16[c * 4 + 2] + sh16[c * 4 + 2]) * d;
            v.w = (h.w * sc16[c * 4 + 3] + sh16[c * 4 + 3]) * d;
        }
        m4[idx] = v;
    }
}

// agg[i] = dis[i] * sum_{j in N(i)} m[j]   (16 floats/row; 16 edge slots x float4)
__global__ void aggregate16_kernel(const float4* __restrict__ m4, const int* __restrict__ csrOff,
                                   const int* __restrict__ csrSrc, const float* __restrict__ dis,
                                   float4* __restrict__ agg4) {
    const int lane = threadIdx.x & 63;
    const int wid = threadIdx.x >> 6;
    const int q = lane >> 2;   // edge slot 0..15
    const int fl = lane & 3;   // float4 column (row = 4 float4s)
    const int wave = blockIdx.x * 4 + wid;
    const int nwaves = gridDim.x * 4;

    for (int n = wave; n < N_NODES; n += nwaves) {
        int beg = csrOff[n], end = csrOff[n + 1];
        float4 acc = make_float4(0.f, 0.f, 0.f, 0.f);
        int e = beg + q;
        int i0 = (e < end) ? csrSrc[e] : N_NODES;
        int i1 = (e + 16 < end) ? csrSrc[e + 16] : N_NODES;
        while (e < end) {
            int j0 = i0, j1 = i1;
            e += 32;
            i0 = (e < end) ? csrSrc[e] : N_NODES;
            i1 = (e + 16 < end) ? csrSrc[e + 16] : N_NODES;
            float4 v0 = m4[(size_t)j0 * 4 + fl];
            float4 v1 = m4[(size_t)j1 * 4 + fl];
            acc.x += v0.x + v1.x; acc.y += v0.y + v1.y;
            acc.z += v0.z + v1.z; acc.w += v0.w + v1.w;
        }
        acc.x += __shfl_xor(acc.x, 4, 64);
        acc.y += __shfl_xor(acc.y, 4, 64);
        acc.z += __shfl_xor(acc.z, 4, 64);
        acc.w += __shfl_xor(acc.w, 4, 64);
        acc.x += __shfl_xor(acc.x, 8, 64);
        acc.y += __shfl_xor(acc.y, 8, 64);
        acc.z += __shfl_xor(acc.z, 8, 64);
        acc.w += __shfl_xor(acc.w, 8, 64);
        acc.x += __shfl_xor(acc.x, 16, 64);
        acc.y += __shfl_xor(acc.y, 16, 64);
        acc.z += __shfl_xor(acc.z, 16, 64);
        acc.w += __shfl_xor(acc.w, 16, 64);
        acc.x += __shfl_xor(acc.x, 32, 64);
        acc.y += __shfl_xor(acc.y, 32, 64);
        acc.z += __shfl_xor(acc.z, 32, 64);
        acc.w += __shfl_xor(acc.w, 32, 64);
        if (q == 0) {
            float d = dis[n];
            acc.x *= d; acc.y *= d; acc.z *= d; acc.w *= d;
            agg4[(size_t)n * 4 + fl] = acc;
        }
    }
}

// y = agg @ W0 + b0 ; accumulate BN stats of y into replicas
#define G16P_ROWS 64
__global__ void gemm16p_kernel(const float* __restrict__ agg, const float* __restrict__ W,
                               const float* __restrict__ bias, float* __restrict__ y,
                               float* __restrict__ statsRep) {
    __shared__ float Ws[IN_DIM][HID];
    __shared__ float xs[G16P_ROWS][IN_DIM + 1];
    __shared__ float ls[4][64], lq[4][64];
    int t = threadIdx.x, f = t & 63, nl = t >> 6;
    for (int i = t; i < IN_DIM * HID; i += 256) Ws[i >> 6][i & 63] = W[i];
    int base = blockIdx.x * G16P_ROWS;
    for (int i = t; i < G16P_ROWS * IN_DIM; i += 256) {
        int r = i >> 4, k = i & 15;
        int n = base + r;
        xs[r][k] = (n < N_NODES) ? agg[n * IN_DIM + k] : 0.f;
    }
    __syncthreads();
    float b = bias[f];
    float acc[16];
#pragma unroll
    for (int r = 0; r < 16; r++) acc[r] = 0.f;
    for (int k = 0; k < IN_DIM; k++) {
        float wk = Ws[k][f];
#pragma unroll
        for (int r = 0; r < 16; r++) acc[r] += xs[nl * 16 + r][k] * wk;
    }
    float sv = 0.f, qv = 0.f;
#pragma unroll
    for (int r = 0; r < 16; r++) {
        int n = base + nl * 16 + r;
        if (n < N_NODES) {
            float val = acc[r] + b;
            y[n * HID + f] = val;
            sv += val;
            qv += val * val;
        }
    }
    ls[nl][f] = sv;
    lq[nl][f] = qv;
    __syncthreads();
    if (nl == 0) {
        float S = ls[0][f] + ls[1][f] + ls[2][f] + ls[3][f];
        float Q = lq[0][f] + lq[1][f] + lq[2][f] + lq[3][f];
        float* rep = statsRep + (blockIdx.x & (NREP - 1)) * 128;
        atomicAdd(&rep[f], S);
        atomicAdd(&rep[64 + f], Q);
    }
}

// ---------------- GEMM 64x64 (BN finalize + relu fused on input) ----------------

#define G64_ROWS 128
__global__ void gemm64_kernel(const float* __restrict__ hin, const float* __restrict__ W,
                              const float* __restrict__ sums, const float* __restrict__ sumsq,
                              const float* __restrict__ gamma, const float* __restrict__ beta,
                              const float* __restrict__ dis, float* __restrict__ hout) {
    __shared__ float Ws[HID * HID];          // [k][f], f contiguous
    __shared__ float hs[G64_ROWS][HID + 1];  // +1 pad
    __shared__ float scb[64], shb[64];
    int t = threadIdx.x;
    int fg = t & 15;
    int rg = t >> 4;
    int base = blockIdx.x * G64_ROWS;

    if (t < 64) bn_coef(sums, sumsq, gamma, beta, t, scb[t], shb[t]);
    {
        const float4* W4 = (const float4*)W;
        float4* Ws4 = (float4*)Ws;
        for (int i = t; i < HID * HID / 4; i += 256) Ws4[i] = W4[i];
    }
    __syncthreads();
    {
        const float4* hin4 = (const float4*)hin;
        for (int i = t; i < G64_ROWS * 16; i += 256) {
            int r = i >> 4, c = i & 15;
            int n = base + r;
            float4 v = make_float4(0.f, 0.f, 0.f, 0.f);
            if (n < N_NODES) {
                float4 h = hin4[n * 16 + c];
                v.x = fmaxf(h.x * scb[c * 4 + 0] + shb[c * 4 + 0], 0.f);
                v.y = fmaxf(h.y * scb[c * 4 + 1] + shb[c * 4 + 1], 0.f);
                v.z = fmaxf(h.z * scb[c * 4 + 2] + shb[c * 4 + 2], 0.f);
                v.w = fmaxf(h.w * scb[c * 4 + 3] + shb[c * 4 + 3], 0.f);
            }
            hs[r][c * 4 + 0] = v.x;
            hs[r][c * 4 + 1] = v.y;
            hs[r][c * 4 + 2] = v.z;
            hs[r][c * 4 + 3] = v.w;
        }
    }
    __syncthreads();

    float4 acc[8];
#pragma unroll
    for (int r = 0; r < 8; r++) acc[r] = make_float4(0.f, 0.f, 0.f, 0.f);
    const float4* Ws4 = (const float4*)Ws;
    for (int k = 0; k < HID; k++) {
        float4 wk = Ws4[k * 16 + fg];
#pragma unroll
        for (int r = 0; r < 8; r++) {
            float h = hs[rg * 8 + r][k];
            acc[r].x += h * wk.x;
            acc[r].y += h * wk.y;
            acc[r].z += h * wk.z;
            acc[r].w += h * wk.w;
        }
    }
    float4* hout4 = (float4*)hout;
#pragma unroll
    for (int r = 0; r < 8; r++) {
        int n = base + rg * 8 + r;
        if (n < N_NODES) {
            float dsc = dis[n];
            float4 o = acc[r];
            o.x *= dsc; o.y *= dsc; o.z *= dsc; o.w *= dsc;
            hout4[n * 16 + fg] = o;
        }
    }
}

// ---------------- Aggregation 64-dim (layers 1-2): pair-interleaved f32 ----------------

__global__ void aggregate_kernel(const float4* __restrict__ hw4, const int* __restrict__ csrOff,
                                 const int* __restrict__ csrSrc, const float* __restrict__ dis,
                                 const float* __restrict__ bias, float4* __restrict__ y4,
                                 float* __restrict__ statsRep) {
    const int lane = threadIdx.x & 63;
    const int wid = threadIdx.x >> 6;
    const int q = lane >> 4;   // edge slot 0..3
    const int fl = lane & 15;  // float4 column
    const int wave = blockIdx.x * 4 + wid;
    const int nwaves = gridDim.x * 4;

    const float4 bias4 = ((const float4*)bias)[fl];
    float4 s_acc = make_float4(0.f, 0.f, 0.f, 0.f);
    float4 q_acc = make_float4(0.f, 0.f, 0.f, 0.f);

    for (int nA = wave; nA < N_NODES; nA += 2 * nwaves) {
        int nB = nA + nwaves;
        bool hasB = (nB < N_NODES);
        int begA = csrOff[nA], endA = csrOff[nA + 1];
        int begB = 0, endB = 0;
        if (hasB) { begB = csrOff[nB]; endB = csrOff[nB + 1]; }
        float4 accA = make_float4(0.f, 0.f, 0.f, 0.f);
        float4 accB = make_float4(0.f, 0.f, 0.f, 0.f);
        int eA = begA + q, eB = begB + q;
        int iA0 = (eA < endA) ? csrSrc[eA] : N_NODES;
        int iA1 = (eA + 4 < endA) ? csrSrc[eA + 4] : N_NODES;
        int iB0 = (eB < endB) ? csrSrc[eB] : N_NODES;
        int iB1 = (eB + 4 < endB) ? csrSrc[eB + 4] : N_NODES;
        while (eA < endA || eB < endB) {
            int jA0 = iA0, jA1 = iA1, jB0 = iB0, jB1 = iB1;
            eA += 8; eB += 8;
            iA0 = (eA < endA) ? csrSrc[eA] : N_NODES;
            iA1 = (eA + 4 < endA) ? csrSrc[eA + 4] : N_NODES;
            iB0 = (eB < endB) ? csrSrc[eB] : N_NODES;
            iB1 = (eB + 4 < endB) ? csrSrc[eB + 4] : N_NODES;
            float4 vA0 = hw4[(size_t)jA0 * 16 + fl];
            float4 vA1 = hw4[(size_t)jA1 * 16 + fl];
            float4 vB0 = hw4[(size_t)jB0 * 16 + fl];
            float4 vB1 = hw4[(size_t)jB1 * 16 + fl];
            accA.x += vA0.x + vA1.x; accA.y += vA0.y + vA1.y;
            accA.z += vA0.z + vA1.z; accA.w += vA0.w + vA1.w;
            accB.x += vB0.x + vB1.x; accB.y += vB0.y + vB1.y;
            accB.z += vB0.z + vB1.z; accB.w += vB0.w + vB1.w;
        }
        accA.x += __shfl_xor(accA.x, 16, 64);
        accA.y += __shfl_xor(accA.y, 16, 64);
        accA.z += __shfl_xor(accA.z, 16, 64);
        accA.w += __shfl_xor(accA.w, 16, 64);
        accA.x += __shfl_xor(accA.x, 32, 64);
        accA.y += __shfl_xor(accA.y, 32, 64);
        accA.z += __shfl_xor(accA.z, 32, 64);
        accA.w += __shfl_xor(accA.w, 32, 64);
        accB.x += __shfl_xor(accB.x, 16, 64);
        accB.y += __shfl_xor(accB.y, 16, 64);
        accB.z += __shfl_xor(accB.z, 16, 64);
        accB.w += __shfl_xor(accB.w, 16, 64);
        accB.x += __shfl_xor(accB.x, 32, 64);
        accB.y += __shfl_xor(accB.y, 32, 64);
        accB.z += __shfl_xor(accB.z, 32, 64);
        accB.w += __shfl_xor(accB.w, 32, 64);
        if (q == 0) {
            float dA = dis[nA];
            float4 valA;
            valA.x = accA.x * dA + bias4.x;
            valA.y = accA.y * dA + bias4.y;
            valA.z = accA.z * dA + bias4.z;
            valA.w = accA.w * dA + bias4.w;
            y4[(size_t)nA * 16 + fl] = valA;
            s_acc.x += valA.x; s_acc.y += valA.y; s_acc.z += valA.z; s_acc.w += valA.w;
            q_acc.x += valA.x * valA.x; q_acc.y += valA.y * valA.y;
            q_acc.z += valA.z * valA.z; q_acc.w += valA.w * valA.w;
            if (hasB) {
                float dB = dis[nB];
                float4 valB;
                valB.x = accB.x * dB + bias4.x;
                valB.y = accB.y * dB + bias4.y;
                valB.z = accB.z * dB + bias4.z;
                valB.w = accB.w * dB + bias4.w;
                y4[(size_t)nB * 16 + fl] = valB;
                s_acc.x += valB.x; s_acc.y += valB.y; s_acc.z += valB.z; s_acc.w += valB.w;
                q_acc.x += valB.x * valB.x; q_acc.y += valB.y * valB.y;
                q_acc.z += valB.z * valB.z; q_acc.w += valB.w * valB.w;
            }
        }
    }
    __shared__ float ls[4][64], lq[4][64];
    ls[wid][lane] = 0.f;
    lq[wid][lane] = 0.f;
    if (q == 0) {
        ls[wid][fl * 4 + 0] = s_acc.x; ls[wid][fl * 4 + 1] = s_acc.y;
        ls[wid][fl * 4 + 2] = s_acc.z; ls[wid][fl * 4 + 3] = s_acc.w;
        lq[wid][fl * 4 + 0] = q_acc.x; lq[wid][fl * 4 + 1] = q_acc.y;
        lq[wid][fl * 4 + 2] = q_acc.z; lq[wid][fl * 4 + 3] = q_acc.w;
    }
    __syncthreads();
    if (wid == 0) {
        float S = ls[0][lane] + ls[1][lane] + ls[2][lane] + ls[3][lane];
        float Q = lq[0][lane] + lq[1][lane] + lq[2][lane] + lq[3][lane];
        float* rep = statsRep + (blockIdx.x & (NREP - 1)) * 128;
        atomicAdd(&rep[lane], S);
        atomicAdd(&rep[64 + lane], Q);
    }
}

// ---------------- Pool (BN finalize fused) + head ----------------

#define POOL_CHUNK 256
__global__ void pool_kernel(const float* __restrict__ y, const int* __restrict__ batch,
                            const float* __restrict__ sums, const float* __restrict__ sumsq,
                            const float* __restrict__ gamma, const float* __restrict__ beta,
                            float* __restrict__ pool, float* __restrict__ cnt) {
    int f = threadIdx.x & 63;
    int nl = threadIdx.x >> 6;
    float sc, sh;
    bn_coef(sums, sumsq, gamma, beta, f, sc, sh);
    int base = blockIdx.x * POOL_CHUNK;
    int endn = min(base + POOL_CHUNK, N_NODES);
    int g_cur = -1;
    float acc = 0.f;
    float c_acc = 0.f;
    for (int n = base + nl; n < endn; n += 4) {
        int g = batch[n];
        float v = fmaxf(y[n * HID + f] * sc + sh, 0.f);
        if (g != g_cur) {
            if (g_cur >= 0) {
                atomicAdd(&pool[g_cur * HID + f], acc);
                if (f == 0) atomicAdd(&cnt[g_cur], c_acc);
            }
            g_cur = g;
            acc = 0.f;
            c_acc = 0.f;
        }
        acc += v;
        c_acc += 1.f;
    }
    if (g_cur >= 0) {
        atomicAdd(&pool[g_cur * HID + f], acc);
        if (f == 0) atomicAdd(&cnt[g_cur], c_acc);
    }
}

__global__ void head_kernel(const float* __restrict__ pool, const float* __restrict__ cnt,
                            const float* __restrict__ Wc1, const float* __restrict__ bc1,
                            const float* __restrict__ Wc2, const float* __restrict__ bc2,
                            float* __restrict__ out) {
    int g = blockIdx.x;
    int f = threadIdx.x;  // 64 threads
    __shared__ float p[64], z[64];
    float c = fmaxf(cnt[g], 1.0f);
    p[f] = pool[g * HID + f] / c;
    __syncthreads();
    float acc = bc1[f];
    for (int k = 0; k < 64; k++) acc += p[k] * Wc1[k * 64 + f];
    z[f] = fmaxf(acc, 0.f);
    __syncthreads();
    if (f < 2) {
        float o = bc2[f];
        for (int k = 0; k < 64; k++) o += z[k] * Wc2[k * 2 + f];
        out[g * 2 + f] = o;
    }
}

// ---------------- launch ----------------

extern "C" void kernel_launch(void* const* d_in, const int* in_sizes, int n_in,
                              void* d_out, int out_size, void* d_ws, size_t ws_size,
                              hipStream_t stream) {
    const float* x      = (const float*)d_in[0];
    const int*   ei     = (const int*)d_in[1];
    const int*   batch  = (const int*)d_in[2];
    const float* bn_in_g = (const float*)d_in[3];
    const float* bn_in_b = (const float*)d_in[4];
    const float* W0 = (const float*)d_in[5];
    const float* b0 = (const float*)d_in[6];
    const float* g0 = (const float*)d_in[7];
    const float* be0 = (const float*)d_in[8];
    const float* W1 = (const float*)d_in[9];
    const float* b1 = (const float*)d_in[10];
    const float* g1 = (const float*)d_in[11];
    const float* be1 = (const float*)d_in[12];
    const float* W2 = (const float*)d_in[13];
    const float* b2 = (const float*)d_in[14];
    const float* g2 = (const float*)d_in[15];
    const float* be2 = (const float*)d_in[16];
    const float* Wc1 = (const float*)d_in[17];
    const float* bc1 = (const float*)d_in[18];
    const float* Wc2 = (const float*)d_in[19];
    const float* bc2 = (const float*)d_in[20];
    float* out = (float*)d_out;

    char* w = (char*)d_ws;
    size_t off = 0;
    auto take = [&](size_t bytes) {
        size_t r = off;
        off += (bytes + 255) & ~(size_t)255;
        return r;
    };
    // ---- zero region (one memset) ----
    float* stats    = (float*)(w + take(4 * 256 * 4));  // slot l: [sums 64][sumsq 64]
    float* statsRep = (float*)(w + take(3 * NREP * 128 * 4));  // replicated accumulators
    float* pool     = (float*)(w + take((size_t)N_GRAPHS * HID * 4));
    float* cnt      = (float*)(w + take((size_t)N_GRAPHS * 4));
    int* bucketCnt  = (int*)(w + take((size_t)NB_BUCKETS * 4));
    size_t zero_end = off;
    // ---- rest ----
    float* dis    = (float*)(w + take((size_t)N_NODES * 4));
    int* csrOff   = (int*)(w + take((size_t)(N_NODES + 1) * 4));
    int* csrSrc   = (int*)(w + take((size_t)(CSR_LEN + 64) * 4));
    float* hwBuf  = (float*)(w + take((size_t)(N_NODES + 1) * HID * 4));  // +dummy zero row
    float* yBuf   = (float*)(w + take((size_t)N_NODES * HID * 4));
    float* aggBuf = (float*)(w + take((size_t)N_NODES * IN_DIM * 4));
    int* regions  = (int*)hwBuf;   // alias: consumed by build_kernel before premsg
    float* msgBuf = (float*)hwBuf; // alias: m[(N+1),16] consumed by aggregate16 before gemm64
    (void)ws_size; (void)n_in; (void)in_sizes; (void)out_size;

    hipMemsetAsync(w, 0, zero_end, stream);

    const int nbBin  = (N_EDGES + BIN_TILE - 1) / BIN_TILE;  // 293
    const int nbPre  = ((N_NODES + 1) * 4 + 255) / 256;
    const int nbG16p = (N_NODES + G16P_ROWS - 1) / G16P_ROWS;
    const int nbG64  = (N_NODES + G64_ROWS - 1) / G64_ROWS;
    const int nbAgg  = 2048;

    // CSR build (bucketed; self-loops folded in)
    bin_kernel<<<nbBin, 256, 0, stream>>>(ei, bucketCnt, regions);
    build_kernel<<<NB_BUCKETS, 256, 0, stream>>>(regions, bucketCnt, csrOff, csrSrc, dis);

    float* s0 = stats + 0 * 256;
    float* s1 = stats + 1 * 256;
    float* s2 = stats + 2 * 256;
    float* s3 = stats + 3 * 256;
    float* rep1 = statsRep + 0 * NREP * 128;
    float* rep2 = statsRep + 1 * NREP * 128;
    float* rep3 = statsRep + 2 * NREP * 128;

    // input BN stats (also zeroes hwBuf dummy row)
    stats_x<<<256, 256, 0, stream>>>(x, s0, s0 + 64, hwBuf);

    // layer 0: pre-aggregate 16-dim, then GEMM
    premsg_kernel<<<nbPre, 256, 0, stream>>>(x, s0, s0 + 64, bn_in_g, bn_in_b, dis,
                                             (float4*)msgBuf);
    aggregate16_kernel<<<nbAgg, 256, 0, stream>>>((const float4*)msgBuf, csrOff, csrSrc, dis,
                                                  (float4*)aggBuf);
    gemm16p_kernel<<<nbG16p, 256, 0, stream>>>(aggBuf, W0, b0, yBuf, rep1);
    reduce_stats<<<1, 128, 0, stream>>>(rep1, s1);

    // layer 1
    gemm64_kernel<<<nbG64, 256, 0, stream>>>(yBuf, W1, s1, s1 + 64, g0, be0, dis, hwBuf);
    aggregate_kernel<<<nbAgg, 256, 0, stream>>>((const float4*)hwBuf, csrOff, csrSrc, dis, b1,
                                                (float4*)yBuf, rep2);
    reduce_stats<<<1, 128, 0, stream>>>(rep2, s2);

    // layer 2
    gemm64_kernel<<<nbG64, 256, 0, stream>>>(yBuf, W2, s2, s2 + 64, g1, be1, dis, hwBuf);
    aggregate_kernel<<<nbAgg, 256, 0, stream>>>((const float4*)hwBuf, csrOff, csrSrc, dis, b2,
                                                (float4*)yBuf, rep3);
    reduce_stats<<<1, 128, 0, stream>>>(rep3, s3);

    // pool + head
    const int nbPool = (N_NODES + POOL_CHUNK - 1) / POOL_CHUNK;
    pool_kernel<<<nbPool, 256, 0, stream>>>(yBuf, batch, s3, s3 + 64, g2, be2, pool, cnt);
    head_kernel<<<N_GRAPHS, 64, 0, stream>>>(pool, cnt, Wc1, bc1, Wc2, bc2, out);
}

// Round 9
// 367.769 us; speedup vs baseline: 1.4810x; 1.2504x over previous
//
#include <hip/hip_runtime.h>
#include <hip/hip_bf16.h>

#define N_NODES 100000
#define N_EDGES 1200000
#define N_GRAPHS 512
#define HID 64
#define IN_DIM 16
#define EPS 1e-5f

#define NB_BUCKETS 391   // ceil(N_NODES / BUCKET_SPAN)
#define BUCKET_SPAN 256  // dst >> 8
#define REGION 4096      // per-bucket region capacity (avg real fill ~3069)
#define BIN_TILE 4096    // edges per bin block
#define CSR_LEN (N_EDGES + N_NODES)  // self-loops folded in
#define NREP 64          // stats replicas (atomic de-contention)

// ---------------- CSR build (bucketed, LDS-built, self-loops included) ----------------

__global__ void bin_kernel(const int* __restrict__ ei, int* __restrict__ bucketCnt,
                           int* __restrict__ regions) {
    __shared__ int hist[NB_BUCKETS], basem[NB_BUCKETS], cur[NB_BUCKETS];
    int t = threadIdx.x;
    for (int i = t; i < NB_BUCKETS; i += 256) { hist[i] = 0; cur[i] = 0; }
    __syncthreads();
    int e0 = blockIdx.x * BIN_TILE;
    int srcs[16], dsts[16];
#pragma unroll
    for (int i = 0; i < 16; i++) {
        int e = e0 + t + i * 256;
        if (e < N_EDGES) {
            srcs[i] = ei[e];
            dsts[i] = ei[N_EDGES + e];
            atomicAdd(&hist[dsts[i] >> 8], 1);
        } else {
            dsts[i] = -1;
        }
    }
    __syncthreads();
    for (int i = t; i < NB_BUCKETS; i += 256) {
        int h = hist[i];
        basem[i] = h ? atomicAdd(&bucketCnt[i], h) : 0;
    }
    __syncthreads();
#pragma unroll
    for (int i = 0; i < 16; i++) {
        if (dsts[i] >= 0) {
            int b = dsts[i] >> 8;
            int pos = basem[b] + atomicAdd(&cur[b], 1);
            if (pos < REGION)
                regions[b * REGION + pos] = srcs[i] | ((dsts[i] & 255) << 17);
        }
    }
}

__global__ void build_kernel(const int* __restrict__ regions, const int* __restrict__ bucketCnt,
                             int* __restrict__ csrOff, int* __restrict__ csrSrc,
                             float* __restrict__ dis) {
    __shared__ int deg[256], off[256], cur[256];
    __shared__ int slice[REGION + 256];
    __shared__ int sTot, sBase;
    int b = blockIdx.x, t = threadIdx.x;
    {
        int s = 0;
        for (int i = t; i < NB_BUCKETS; i += 256)
            if (i < b) s += min(bucketCnt[i], REGION);
        deg[t] = s;
        __syncthreads();
        for (int k = 128; k > 0; k >>= 1) {
            if (t < k) deg[t] += deg[t + k];
            __syncthreads();
        }
        if (t == 0) sBase = deg[0] + b * BUCKET_SPAN;
        __syncthreads();
    }
    int bb = sBase;
    int cnt = min(bucketCnt[b], REGION);
    int nbase = b * BUCKET_SPAN;
    int n = nbase + t;
    bool valid = (n < N_NODES);
    deg[t] = valid ? 1 : 0;  // self loop
    __syncthreads();
    for (int i = t; i < cnt; i += 256) {
        int rec = regions[b * REGION + i];
        atomicAdd(&deg[rec >> 17], 1);
    }
    __syncthreads();
    int d = deg[t];
    off[t] = d;
    __syncthreads();
    for (int s = 1; s < 256; s <<= 1) {
        int v = (t >= s) ? off[t - s] : 0;
        __syncthreads();
        off[t] += v;
        __syncthreads();
    }
    int excl = off[t] - d;
    if (valid) {
        csrOff[n] = bb + excl;
        dis[n] = rsqrtf((float)d);
    }
    if (b == 0 && t == 0) csrOff[N_NODES] = CSR_LEN;
    if (t == 255) sTot = off[255];
    cur[t] = excl;
    __syncthreads();
    if (valid) {
        int pos = atomicAdd(&cur[t], 1);
        slice[pos] = n;
    }
    for (int i = t; i < cnt; i += 256) {
        int rec = regions[b * REGION + i];
        int pos = atomicAdd(&cur[rec >> 17], 1);
        slice[pos] = rec & 0x1FFFF;
    }
    __syncthreads();
    int tot = sTot;
    for (int i = t; i < tot; i += 256) csrSrc[bb + i] = slice[i];
}

// ---------------- BN statistics over x (also zeroes the 64-dim dummy gather row) -------

__global__ void stats_x(const float* __restrict__ x, float* __restrict__ sums,
                        float* __restrict__ sumsq, float* __restrict__ hwBuf) {
    __shared__ float ls[16], lq[16];
    int t = threadIdx.x;
    if (blockIdx.x == 0 && t < 16)
        ((float4*)(hwBuf + (size_t)N_NODES * HID))[t] = make_float4(0.f, 0.f, 0.f, 0.f);
    if (t < 16) { ls[t] = 0.f; lq[t] = 0.f; }
    __syncthreads();
    float s = 0.f, q = 0.f;
    const int total = N_NODES * IN_DIM;
    for (int i = blockIdx.x * blockDim.x + t; i < total; i += gridDim.x * blockDim.x) {
        float v = x[i];
        s += v; q += v * v;
    }
    int k = t & 15;
    atomicAdd(&ls[k], s);
    atomicAdd(&lq[k], q);
    __syncthreads();
    if (t < 16) { atomicAdd(&sums[t], ls[t]); atomicAdd(&sumsq[t], lq[t]); }
}

__device__ __forceinline__ void bn_coef(const float* sums, const float* sumsq,
                                        const float* gamma, const float* beta, int k,
                                        float& sc, float& sh) {
    const float invn = 1.0f / (float)N_NODES;
    float m = sums[k] * invn;
    float var = sumsq[k] * invn - m * m;
    float rs = rsqrtf(var + EPS);
    sc = gamma[k] * rs;
    sh = beta[k] - m * sc;
}

// fold NREP stats replicas ([NREP][128]) into canonical [sums 64 | sumsq 64]
__global__ void reduce_stats(const float* __restrict__ rep, float* __restrict__ outStats) {
    int j = threadIdx.x;  // 0..127
    float s = 0.f;
    for (int r = 0; r < NREP; r++) s += rep[r * 128 + j];
    outStats[j] = s;
}

// ---------------- Layer 0: premsg + fused aggregate16·W0 ----------------

// m[n] = BN(x[n]) * dis[n]  (16 floats/row); zeroes dummy row N_NODES
__global__ void premsg_kernel(const float* __restrict__ x, const float* __restrict__ sums,
                              const float* __restrict__ sumsq, const float* __restrict__ gamma,
                              const float* __restrict__ beta, const float* __restrict__ dis,
                              float4* __restrict__ m4) {
    __shared__ float sc16[16], sh16[16];
    int t = threadIdx.x;
    if (t < 16) bn_coef(sums, sumsq, gamma, beta, t, sc16[t], sh16[t]);
    __syncthreads();
    int idx = blockIdx.x * 256 + t;  // float4 index
    if (idx < (N_NODES + 1) * 4) {
        int n = idx >> 2, c = idx & 3;
        float4 v = make_float4(0.f, 0.f, 0.f, 0.f);
        if (n < N_NODES) {
            float4 h = ((const float4*)x)[idx];
            float d = dis[n];
            v.x = (h.x * sc16[c * 4 + 0] + sh16[c * 4 + 0]) * d;
            v.y = (h.y * sc16[c * 4 + 1] + sh16[c * 4 + 1]) * d;
            v.z = (h.z * sc16[c * 4 + 2] + sh16[c * 4 + 2]) * d;
            v.w = (h.w * sc16[c * 4 + 3] + sh16[c * 4 + 3]) * d;
        }
        m4[idx] = v;
    }
}

// y[n,f] = (dis[n] * sum_{j in N(i)} m[j]) @ W0 + b0 ; BN stats into replicas.
// 16 edge slots x float4; after slot-reduce each lane holds agg[4fl..4fl+3],
// shfl-collect 16 values, 16 FMAs vs LDS W0, coalesced 256B row store.
__global__ void agg16_gemm0_kernel(const float4* __restrict__ m4, const int* __restrict__ csrOff,
                                   const int* __restrict__ csrSrc, const float* __restrict__ dis,
                                   const float* __restrict__ W, const float* __restrict__ bias,
                                   float* __restrict__ y, float* __restrict__ statsRep) {
    __shared__ float Ws[IN_DIM][HID];
    int t = threadIdx.x;
    for (int i = t; i < IN_DIM * HID; i += 256) Ws[i >> 6][i & 63] = W[i];
    __syncthreads();
    const int lane = t & 63;
    const int wid = t >> 6;
    const int q = lane >> 2;   // edge slot 0..15
    const int fl = lane & 3;   // float4 column
    const int baseLane = lane & ~3;
    const int wave = blockIdx.x * 4 + wid;
    const int nwaves = gridDim.x * 4;
    float b = bias[lane];
    float sv = 0.f, qv = 0.f;

    for (int n = wave; n < N_NODES; n += nwaves) {
        int beg = csrOff[n], end = csrOff[n + 1];
        float4 acc = make_float4(0.f, 0.f, 0.f, 0.f);
        int e = beg + q;
        int i0 = (e < end) ? csrSrc[e] : N_NODES;
        int i1 = (e + 16 < end) ? csrSrc[e + 16] : N_NODES;
        while (e < end) {
            int j0 = i0, j1 = i1;
            e += 32;
            i0 = (e < end) ? csrSrc[e] : N_NODES;
            i1 = (e + 16 < end) ? csrSrc[e + 16] : N_NODES;
            float4 v0 = m4[(size_t)j0 * 4 + fl];
            float4 v1 = m4[(size_t)j1 * 4 + fl];
            acc.x += v0.x + v1.x; acc.y += v0.y + v1.y;
            acc.z += v0.z + v1.z; acc.w += v0.w + v1.w;
        }
#pragma unroll
        for (int m = 4; m <= 32; m <<= 1) {
            acc.x += __shfl_xor(acc.x, m, 64);
            acc.y += __shfl_xor(acc.y, m, 64);
            acc.z += __shfl_xor(acc.z, m, 64);
            acc.w += __shfl_xor(acc.w, m, 64);
        }
        float d = dis[n];
        acc.x *= d; acc.y *= d; acc.z *= d; acc.w *= d;
        // every lane now holds agg[4fl..4fl+3]; collect all 16 and GEMM
        float yv = b;
#pragma unroll
        for (int sf = 0; sf < 4; sf++) {
            float ax = __shfl(acc.x, baseLane + sf, 64);
            float ay = __shfl(acc.y, baseLane + sf, 64);
            float az = __shfl(acc.z, baseLane + sf, 64);
            float aw = __shfl(acc.w, baseLane + sf, 64);
            yv += ax * Ws[sf * 4 + 0][lane];
            yv += ay * Ws[sf * 4 + 1][lane];
            yv += az * Ws[sf * 4 + 2][lane];
            yv += aw * Ws[sf * 4 + 3][lane];
        }
        y[(size_t)n * HID + lane] = yv;
        sv += yv;
        qv += yv * yv;
    }
    __shared__ float ls[4][64], lq[4][64];
    ls[wid][lane] = sv;
    lq[wid][lane] = qv;
    __syncthreads();
    if (wid == 0) {
        float S = ls[0][lane] + ls[1][lane] + ls[2][lane] + ls[3][lane];
        float Q = lq[0][lane] + lq[1][lane] + lq[2][lane] + lq[3][lane];
        float* rep = statsRep + (blockIdx.x & (NREP - 1)) * 128;
        atomicAdd(&rep[lane], S);
        atomicAdd(&rep[64 + lane], Q);
    }
}

// ---------------- GEMM 64x64 (BN finalize + relu fused on input) ----------------

#define G64_ROWS 128
__global__ void gemm64_kernel(const float* __restrict__ hin, const float* __restrict__ W,
                              const float* __restrict__ sums, const float* __restrict__ sumsq,
                              const float* __restrict__ gamma, const float* __restrict__ beta,
                              const float* __restrict__ dis, float* __restrict__ hout) {
    __shared__ float Ws[HID * HID];          // [k][f], f contiguous
    __shared__ float hs[G64_ROWS][HID + 1];  // +1 pad
    __shared__ float scb[64], shb[64];
    int t = threadIdx.x;
    int fg = t & 15;
    int rg = t >> 4;
    int base = blockIdx.x * G64_ROWS;

    if (t < 64) bn_coef(sums, sumsq, gamma, beta, t, scb[t], shb[t]);
    {
        const float4* W4 = (const float4*)W;
        float4* Ws4 = (float4*)Ws;
        for (int i = t; i < HID * HID / 4; i += 256) Ws4[i] = W4[i];
    }
    __syncthreads();
    {
        const float4* hin4 = (const float4*)hin;
        for (int i = t; i < G64_ROWS * 16; i += 256) {
            int r = i >> 4, c = i & 15;
            int n = base + r;
            float4 v = make_float4(0.f, 0.f, 0.f, 0.f);
            if (n < N_NODES) {
                float4 h = hin4[n * 16 + c];
                v.x = fmaxf(h.x * scb[c * 4 + 0] + shb[c * 4 + 0], 0.f);
                v.y = fmaxf(h.y * scb[c * 4 + 1] + shb[c * 4 + 1], 0.f);
                v.z = fmaxf(h.z * scb[c * 4 + 2] + shb[c * 4 + 2], 0.f);
                v.w = fmaxf(h.w * scb[c * 4 + 3] + shb[c * 4 + 3], 0.f);
            }
            hs[r][c * 4 + 0] = v.x;
            hs[r][c * 4 + 1] = v.y;
            hs[r][c * 4 + 2] = v.z;
            hs[r][c * 4 + 3] = v.w;
        }
    }
    __syncthreads();

    float4 acc[8];
#pragma unroll
    for (int r = 0; r < 8; r++) acc[r] = make_float4(0.f, 0.f, 0.f, 0.f);
    const float4* Ws4 = (const float4*)Ws;
    for (int k = 0; k < HID; k++) {
        float4 wk = Ws4[k * 16 + fg];
#pragma unroll
        for (int r = 0; r < 8; r++) {
            float h = hs[rg * 8 + r][k];
            acc[r].x += h * wk.x;
            acc[r].y += h * wk.y;
            acc[r].z += h * wk.z;
            acc[r].w += h * wk.w;
        }
    }
    float4* hout4 = (float4*)hout;
#pragma unroll
    for (int r = 0; r < 8; r++) {
        int n = base + rg * 8 + r;
        if (n < N_NODES) {
            float dsc = dis[n];
            float4 o = acc[r];
            o.x *= dsc; o.y *= dsc; o.z *= dsc; o.w *= dsc;
            hout4[n * 16 + fg] = o;
        }
    }
}

// ---------------- Aggregation 64-dim: single-node depth-2, replica stats ----------------

__global__ void aggregate_kernel(const float4* __restrict__ hw4, const int* __restrict__ csrOff,
                                 const int* __restrict__ csrSrc, const float* __restrict__ dis,
                                 const float* __restrict__ bias, float4* __restrict__ y4,
                                 float* __restrict__ statsRep) {
    const int lane = threadIdx.x & 63;
    const int wid = threadIdx.x >> 6;
    const int q = lane >> 4;   // edge slot 0..3
    const int fl = lane & 15;  // float4 column
    const int wave = blockIdx.x * 4 + wid;
    const int nwaves = gridDim.x * 4;

    const float4 bias4 = ((const float4*)bias)[fl];
    float4 s_acc = make_float4(0.f, 0.f, 0.f, 0.f);
    float4 q_acc = make_float4(0.f, 0.f, 0.f, 0.f);

    for (int n = wave; n < N_NODES; n += nwaves) {
        int beg = csrOff[n], end = csrOff[n + 1];
        float4 acc = make_float4(0.f, 0.f, 0.f, 0.f);
        int e = beg + q;
        int i0 = (e < end) ? csrSrc[e] : N_NODES;
        int i1 = (e + 4 < end) ? csrSrc[e + 4] : N_NODES;
        while (e < end) {
            int j0 = i0, j1 = i1;
            e += 8;
            i0 = (e < end) ? csrSrc[e] : N_NODES;
            i1 = (e + 4 < end) ? csrSrc[e + 4] : N_NODES;
            float4 v0 = hw4[(size_t)j0 * 16 + fl];
            float4 v1 = hw4[(size_t)j1 * 16 + fl];
            acc.x += v0.x + v1.x; acc.y += v0.y + v1.y;
            acc.z += v0.z + v1.z; acc.w += v0.w + v1.w;
        }
        acc.x += __shfl_xor(acc.x, 16, 64);
        acc.y += __shfl_xor(acc.y, 16, 64);
        acc.z += __shfl_xor(acc.z, 16, 64);
        acc.w += __shfl_xor(acc.w, 16, 64);
        acc.x += __shfl_xor(acc.x, 32, 64);
        acc.y += __shfl_xor(acc.y, 32, 64);
        acc.z += __shfl_xor(acc.z, 32, 64);
        acc.w += __shfl_xor(acc.w, 32, 64);
        if (q == 0) {
            float d = dis[n];
            float4 val;
            val.x = acc.x * d + bias4.x;
            val.y = acc.y * d + bias4.y;
            val.z = acc.z * d + bias4.z;
            val.w = acc.w * d + bias4.w;
            y4[(size_t)n * 16 + fl] = val;
            s_acc.x += val.x; s_acc.y += val.y; s_acc.z += val.z; s_acc.w += val.w;
            q_acc.x += val.x * val.x; q_acc.y += val.y * val.y;
            q_acc.z += val.z * val.z; q_acc.w += val.w * val.w;
        }
    }
    __shared__ float ls[4][64], lq[4][64];
    ls[wid][lane] = 0.f;
    lq[wid][lane] = 0.f;
    if (q == 0) {
        ls[wid][fl * 4 + 0] = s_acc.x; ls[wid][fl * 4 + 1] = s_acc.y;
        ls[wid][fl * 4 + 2] = s_acc.z; ls[wid][fl * 4 + 3] = s_acc.w;
        lq[wid][fl * 4 + 0] = q_acc.x; lq[wid][fl * 4 + 1] = q_acc.y;
        lq[wid][fl * 4 + 2] = q_acc.z; lq[wid][fl * 4 + 3] = q_acc.w;
    }
    __syncthreads();
    if (wid == 0) {
        float S = ls[0][lane] + ls[1][lane] + ls[2][lane] + ls[3][lane];
        float Q = lq[0][lane] + lq[1][lane] + lq[2][lane] + lq[3][lane];
        float* rep = statsRep + (blockIdx.x & (NREP - 1)) * 128;
        atomicAdd(&rep[lane], S);
        atomicAdd(&rep[64 + lane], Q);
    }
}

// ---------------- Pool (BN finalize fused) + head ----------------

#define POOL_CHUNK 256
__global__ void pool_kernel(const float* __restrict__ y, const int* __restrict__ batch,
                            const float* __restrict__ sums, const float* __restrict__ sumsq,
                            const float* __restrict__ gamma, const float* __restrict__ beta,
                            float* __restrict__ pool, float* __restrict__ cnt) {
    int f = threadIdx.x & 63;
    int nl = threadIdx.x >> 6;
    float sc, sh;
    bn_coef(sums, sumsq, gamma, beta, f, sc, sh);
    int base = blockIdx.x * POOL_CHUNK;
    int endn = min(base + POOL_CHUNK, N_NODES);
    int g_cur = -1;
    float acc = 0.f;
    float c_acc = 0.f;
    for (int n = base + nl; n < endn; n += 4) {
        int g = batch[n];
        float v = fmaxf(y[n * HID + f] * sc + sh, 0.f);
        if (g != g_cur) {
            if (g_cur >= 0) {
                atomicAdd(&pool[g_cur * HID + f], acc);
                if (f == 0) atomicAdd(&cnt[g_cur], c_acc);
            }
            g_cur = g;
            acc = 0.f;
            c_acc = 0.f;
        }
        acc += v;
        c_acc += 1.f;
    }
    if (g_cur >= 0) {
        atomicAdd(&pool[g_cur * HID + f], acc);
        if (f == 0) atomicAdd(&cnt[g_cur], c_acc);
    }
}

__global__ void head_kernel(const float* __restrict__ pool, const float* __restrict__ cnt,
                            const float* __restrict__ Wc1, const float* __restrict__ bc1,
                            const float* __restrict__ Wc2, const float* __restrict__ bc2,
                            float* __restrict__ out) {
    int g = blockIdx.x;
    int f = threadIdx.x;  // 64 threads
    __shared__ float p[64], z[64];
    float c = fmaxf(cnt[g], 1.0f);
    p[f] = pool[g * HID + f] / c;
    __syncthreads();
    float acc = bc1[f];
    for (int k = 0; k < 64; k++) acc += p[k] * Wc1[k * 64 + f];
    z[f] = fmaxf(acc, 0.f);
    __syncthreads();
    if (f < 2) {
        float o = bc2[f];
        for (int k = 0; k < 64; k++) o += z[k] * Wc2[k * 2 + f];
        out[g * 2 + f] = o;
    }
}

// ---------------- launch ----------------

extern "C" void kernel_launch(void* const* d_in, const int* in_sizes, int n_in,
                              void* d_out, int out_size, void* d_ws, size_t ws_size,
                              hipStream_t stream) {
    const float* x      = (const float*)d_in[0];
    const int*   ei     = (const int*)d_in[1];
    const int*   batch  = (const int*)d_in[2];
    const float* bn_in_g = (const float*)d_in[3];
    const float* bn_in_b = (const float*)d_in[4];
    const float* W0 = (const float*)d_in[5];
    const float* b0 = (const float*)d_in[6];
    const float* g0 = (const float*)d_in[7];
    const float* be0 = (const float*)d_in[8];
    const float* W1 = (const float*)d_in[9];
    const float* b1 = (const float*)d_in[10];
    const float* g1 = (const float*)d_in[11];
    const float* be1 = (const float*)d_in[12];
    const float* W2 = (const float*)d_in[13];
    const float* b2 = (const float*)d_in[14];
    const float* g2 = (const float*)d_in[15];
    const float* be2 = (const float*)d_in[16];
    const float* Wc1 = (const float*)d_in[17];
    const float* bc1 = (const float*)d_in[18];
    const float* Wc2 = (const float*)d_in[19];
    const float* bc2 = (const float*)d_in[20];
    float* out = (float*)d_out;

    char* w = (char*)d_ws;
    size_t off = 0;
    auto take = [&](size_t bytes) {
        size_t r = off;
        off += (bytes + 255) & ~(size_t)255;
        return r;
    };
    // ---- zero region (one memset) ----
    float* stats    = (float*)(w + take(4 * 256 * 4));  // slot l: [sums 64][sumsq 64]
    float* statsRep = (float*)(w + take(3 * NREP * 128 * 4));  // replicated accumulators
    float* pool     = (float*)(w + take((size_t)N_GRAPHS * HID * 4));
    float* cnt      = (float*)(w + take((size_t)N_GRAPHS * 4));
    int* bucketCnt  = (int*)(w + take((size_t)NB_BUCKETS * 4));
    size_t zero_end = off;
    // ---- rest ----
    float* dis    = (float*)(w + take((size_t)N_NODES * 4));
    int* csrOff   = (int*)(w + take((size_t)(N_NODES + 1) * 4));
    int* csrSrc   = (int*)(w + take((size_t)(CSR_LEN + 64) * 4));
    float* hwBuf  = (float*)(w + take((size_t)(N_NODES + 1) * HID * 4));  // +dummy zero row
    float* yBuf   = (float*)(w + take((size_t)N_NODES * HID * 4));
    int* regions  = (int*)hwBuf;   // alias: consumed by build_kernel before premsg
    float* msgBuf = (float*)hwBuf; // alias: m[(N+1),16] consumed by agg16_gemm0 before gemm64
    (void)ws_size; (void)n_in; (void)in_sizes; (void)out_size;

    hipMemsetAsync(w, 0, zero_end, stream);

    const int nbBin  = (N_EDGES + BIN_TILE - 1) / BIN_TILE;  // 293
    const int nbPre  = ((N_NODES + 1) * 4 + 255) / 256;
    const int nbG64  = (N_NODES + G64_ROWS - 1) / G64_ROWS;
    const int nbAgg  = 4096;

    // CSR build (bucketed; self-loops folded in)
    bin_kernel<<<nbBin, 256, 0, stream>>>(ei, bucketCnt, regions);
    build_kernel<<<NB_BUCKETS, 256, 0, stream>>>(regions, bucketCnt, csrOff, csrSrc, dis);

    float* s0 = stats + 0 * 256;
    float* s1 = stats + 1 * 256;
    float* s2 = stats + 2 * 256;
    float* s3 = stats + 3 * 256;
    float* rep1 = statsRep + 0 * NREP * 128;
    float* rep2 = statsRep + 1 * NREP * 128;
    float* rep3 = statsRep + 2 * NREP * 128;

    // input BN stats (also zeroes hwBuf 64-dim dummy row)
    stats_x<<<256, 256, 0, stream>>>(x, s0, s0 + 64, hwBuf);

    // layer 0: premsg -> fused 16-dim aggregate + W0 GEMM
    premsg_kernel<<<nbPre, 256, 0, stream>>>(x, s0, s0 + 64, bn_in_g, bn_in_b, dis,
                                             (float4*)msgBuf);
    agg16_gemm0_kernel<<<nbAgg, 256, 0, stream>>>((const float4*)msgBuf, csrOff, csrSrc, dis,
                                                  W0, b0, yBuf, rep1);
    reduce_stats<<<1, 128, 0, stream>>>(rep1, s1);

    // layer 1
    gemm64_kernel<<<nbG64, 256, 0, stream>>>(yBuf, W1, s1, s1 + 64, g0, be0, dis, hwBuf);
    aggregate_kernel<<<nbAgg, 256, 0, stream>>>((const float4*)hwBuf, csrOff, csrSrc, dis, b1,
                                                (float4*)yBuf, rep2);
    reduce_stats<<<1, 128, 0, stream>>>(rep2, s2);

    // layer 2
    gemm64_kernel<<<nbG64, 256, 0, stream>>>(yBuf, W2, s2, s2 + 64, g1, be1, dis, hwBuf);
    aggregate_kernel<<<nbAgg, 256, 0, stream>>>((const float4*)hwBuf, csrOff, csrSrc, dis, b2,
                                                (float4*)yBuf, rep3);
    reduce_stats<<<1, 128, 0, stream>>>(rep3, s3);

    // pool + head
    const int nbPool = (N_NODES + POOL_CHUNK - 1) / POOL_CHUNK;
    pool_kernel<<<nbPool, 256, 0, stream>>>(yBuf, batch, s3, s3 + 64, g2, be2, pool, cnt);
    head_kernel<<<N_GRAPHS, 64, 0, stream>>>(pool, cnt, Wc1, bc1, Wc2, bc2, out);
}

// Round 10
// 344.680 us; speedup vs baseline: 1.5802x; 1.0670x over previous
//
#include <hip/hip_runtime.h>
#include <hip/hip_bf16.h>

#define N_NODES 100000
#define N_EDGES 1200000
#define N_GRAPHS 512
#define HID 64
#define IN_DIM 16
#define EPS 1e-5f

#define NB_BUCKETS 391   // ceil(N_NODES / BUCKET_SPAN)
#define BUCKET_SPAN 256  // dst >> 8
#define REGION 4096      // per-bucket region capacity (avg real fill ~3069)
#define BIN_TILE 4096    // edges per bin block
#define CSR_LEN (N_EDGES + N_NODES)  // self-loops folded in
#define NREP 64          // stats replicas (atomic de-contention)

typedef _Float16 half4 __attribute__((ext_vector_type(4)));
typedef _Float16 half8 __attribute__((ext_vector_type(8)));

// ---------------- CSR build (bucketed, LDS-built, self-loops included) ----------------

__global__ void bin_kernel(const int* __restrict__ ei, int* __restrict__ bucketCnt,
                           int* __restrict__ regions) {
    __shared__ int hist[NB_BUCKETS], basem[NB_BUCKETS], cur[NB_BUCKETS];
    int t = threadIdx.x;
    for (int i = t; i < NB_BUCKETS; i += 256) { hist[i] = 0; cur[i] = 0; }
    __syncthreads();
    int e0 = blockIdx.x * BIN_TILE;
    int srcs[16], dsts[16];
#pragma unroll
    for (int i = 0; i < 16; i++) {
        int e = e0 + t + i * 256;
        if (e < N_EDGES) {
            srcs[i] = ei[e];
            dsts[i] = ei[N_EDGES + e];
            atomicAdd(&hist[dsts[i] >> 8], 1);
        } else {
            dsts[i] = -1;
        }
    }
    __syncthreads();
    for (int i = t; i < NB_BUCKETS; i += 256) {
        int h = hist[i];
        basem[i] = h ? atomicAdd(&bucketCnt[i], h) : 0;
    }
    __syncthreads();
#pragma unroll
    for (int i = 0; i < 16; i++) {
        if (dsts[i] >= 0) {
            int b = dsts[i] >> 8;
            int pos = basem[b] + atomicAdd(&cur[b], 1);
            if (pos < REGION)
                regions[b * REGION + pos] = srcs[i] | ((dsts[i] & 255) << 17);
        }
    }
}

__global__ void build_kernel(const int* __restrict__ regions, const int* __restrict__ bucketCnt,
                             int* __restrict__ csrOff, int* __restrict__ csrSrc,
                             float* __restrict__ dis) {
    __shared__ int deg[256], off[256], cur[256];
    __shared__ int slice[REGION + 256];
    __shared__ int sTot, sBase;
    int b = blockIdx.x, t = threadIdx.x;
    {
        int s = 0;
        for (int i = t; i < NB_BUCKETS; i += 256)
            if (i < b) s += min(bucketCnt[i], REGION);
        deg[t] = s;
        __syncthreads();
        for (int k = 128; k > 0; k >>= 1) {
            if (t < k) deg[t] += deg[t + k];
            __syncthreads();
        }
        if (t == 0) sBase = deg[0] + b * BUCKET_SPAN;
        __syncthreads();
    }
    int bb = sBase;
    int cnt = min(bucketCnt[b], REGION);
    int nbase = b * BUCKET_SPAN;
    int n = nbase + t;
    bool valid = (n < N_NODES);
    deg[t] = valid ? 1 : 0;  // self loop
    __syncthreads();
    for (int i = t; i < cnt; i += 256) {
        int rec = regions[b * REGION + i];
        atomicAdd(&deg[rec >> 17], 1);
    }
    __syncthreads();
    int d = deg[t];
    off[t] = d;
    __syncthreads();
    for (int s = 1; s < 256; s <<= 1) {
        int v = (t >= s) ? off[t - s] : 0;
        __syncthreads();
        off[t] += v;
        __syncthreads();
    }
    int excl = off[t] - d;
    if (valid) {
        csrOff[n] = bb + excl;
        dis[n] = rsqrtf((float)d);
    }
    if (b == 0 && t == 0) csrOff[N_NODES] = CSR_LEN;
    if (t == 255) sTot = off[255];
    cur[t] = excl;
    __syncthreads();
    if (valid) {
        int pos = atomicAdd(&cur[t], 1);
        slice[pos] = n;
    }
    for (int i = t; i < cnt; i += 256) {
        int rec = regions[b * REGION + i];
        int pos = atomicAdd(&cur[rec >> 17], 1);
        slice[pos] = rec & 0x1FFFF;
    }
    __syncthreads();
    int tot = sTot;
    for (int i = t; i < tot; i += 256) csrSrc[bb + i] = slice[i];
}

// ---------------- BN statistics over x (also zeroes the f16 dummy gather row) -------

__global__ void stats_x(const float* __restrict__ x, float* __restrict__ sums,
                        float* __restrict__ sumsq, _Float16* __restrict__ hwBuf) {
    __shared__ float ls[16], lq[16];
    int t = threadIdx.x;
    if (blockIdx.x == 0 && t < 8)  // 64 halfs = 128 B = 8 x 16B
        ((float4*)(hwBuf + (size_t)N_NODES * HID))[t] = make_float4(0.f, 0.f, 0.f, 0.f);
    if (t < 16) { ls[t] = 0.f; lq[t] = 0.f; }
    __syncthreads();
    float s = 0.f, q = 0.f;
    const int total = N_NODES * IN_DIM;
    for (int i = blockIdx.x * blockDim.x + t; i < total; i += gridDim.x * blockDim.x) {
        float v = x[i];
        s += v; q += v * v;
    }
    int k = t & 15;
    atomicAdd(&ls[k], s);
    atomicAdd(&lq[k], q);
    __syncthreads();
    if (t < 16) { atomicAdd(&sums[t], ls[t]); atomicAdd(&sumsq[t], lq[t]); }
}

__device__ __forceinline__ void bn_coef(const float* sums, const float* sumsq,
                                        const float* gamma, const float* beta, int k,
                                        float& sc, float& sh) {
    const float invn = 1.0f / (float)N_NODES;
    float m = sums[k] * invn;
    float var = sumsq[k] * invn - m * m;
    float rs = rsqrtf(var + EPS);
    sc = gamma[k] * rs;
    sh = beta[k] - m * sc;
}

// fold NREP stats replicas ([NREP][128]) into canonical [sums 64 | sumsq 64]
__global__ void reduce_stats(const float* __restrict__ rep, float* __restrict__ outStats) {
    int j = threadIdx.x;  // 0..127
    float s = 0.f;
    for (int r = 0; r < NREP; r++) s += rep[r * 128 + j];
    outStats[j] = s;
}

// ---------------- Layer 0: premsg (f16) + fused aggregate16·W0 ----------------

// m[n] = BN(x[n]) * dis[n]  (16 halfs/row = 32 B); zeroes dummy row N_NODES
__global__ void premsg_kernel(const float* __restrict__ x, const float* __restrict__ sums,
                              const float* __restrict__ sumsq, const float* __restrict__ gamma,
                              const float* __restrict__ beta, const float* __restrict__ dis,
                              half4* __restrict__ m4) {
    __shared__ float sc16[16], sh16[16];
    int t = threadIdx.x;
    if (t < 16) bn_coef(sums, sumsq, gamma, beta, t, sc16[t], sh16[t]);
    __syncthreads();
    int idx = blockIdx.x * 256 + t;  // half4 index
    if (idx < (N_NODES + 1) * 4) {
        int n = idx >> 2, c = idx & 3;
        half4 o;
        o.x = (_Float16)0.f; o.y = (_Float16)0.f; o.z = (_Float16)0.f; o.w = (_Float16)0.f;
        if (n < N_NODES) {
            float4 h = ((const float4*)x)[idx];
            float d = dis[n];
            o.x = (_Float16)((h.x * sc16[c * 4 + 0] + sh16[c * 4 + 0]) * d);
            o.y = (_Float16)((h.y * sc16[c * 4 + 1] + sh16[c * 4 + 1]) * d);
            o.z = (_Float16)((h.z * sc16[c * 4 + 2] + sh16[c * 4 + 2]) * d);
            o.w = (_Float16)((h.w * sc16[c * 4 + 3] + sh16[c * 4 + 3]) * d);
        }
        m4[idx] = o;
    }
}

// y[n,f] = (dis[n] * sum_{j in N(n)} m[j]) @ W0 + b0 ; BN stats into replicas.
__global__ void agg16_gemm0_kernel(const half4* __restrict__ m4, const int* __restrict__ csrOff,
                                   const int* __restrict__ csrSrc, const float* __restrict__ dis,
                                   const float* __restrict__ W, const float* __restrict__ bias,
                                   float* __restrict__ y, float* __restrict__ statsRep) {
    __shared__ float Ws[IN_DIM][HID];
    int t = threadIdx.x;
    for (int i = t; i < IN_DIM * HID; i += 256) Ws[i >> 6][i & 63] = W[i];
    __syncthreads();
    const int lane = t & 63;
    const int wid = t >> 6;
    const int q = lane >> 2;   // edge slot 0..15
    const int fl = lane & 3;   // half4 column
    const int baseLane = lane & ~3;
    const int wave = blockIdx.x * 4 + wid;
    const int nwaves = gridDim.x * 4;
    float b = bias[lane];
    float sv = 0.f, qv = 0.f;

    for (int n = wave; n < N_NODES; n += nwaves) {
        int beg = csrOff[n], end = csrOff[n + 1];
        float4 acc = make_float4(0.f, 0.f, 0.f, 0.f);
        int e = beg + q;
        int i0 = (e < end) ? csrSrc[e] : N_NODES;
        int i1 = (e + 16 < end) ? csrSrc[e + 16] : N_NODES;
        while (e < end) {
            int j0 = i0, j1 = i1;
            e += 32;
            i0 = (e < end) ? csrSrc[e] : N_NODES;
            i1 = (e + 16 < end) ? csrSrc[e + 16] : N_NODES;
            half4 v0 = m4[(size_t)j0 * 4 + fl];
            half4 v1 = m4[(size_t)j1 * 4 + fl];
            acc.x += (float)v0.x + (float)v1.x;
            acc.y += (float)v0.y + (float)v1.y;
            acc.z += (float)v0.z + (float)v1.z;
            acc.w += (float)v0.w + (float)v1.w;
        }
#pragma unroll
        for (int m = 4; m <= 32; m <<= 1) {
            acc.x += __shfl_xor(acc.x, m, 64);
            acc.y += __shfl_xor(acc.y, m, 64);
            acc.z += __shfl_xor(acc.z, m, 64);
            acc.w += __shfl_xor(acc.w, m, 64);
        }
        float d = dis[n];
        acc.x *= d; acc.y *= d; acc.z *= d; acc.w *= d;
        float yv = b;
#pragma unroll
        for (int sf = 0; sf < 4; sf++) {
            float ax = __shfl(acc.x, baseLane + sf, 64);
            float ay = __shfl(acc.y, baseLane + sf, 64);
            float az = __shfl(acc.z, baseLane + sf, 64);
            float aw = __shfl(acc.w, baseLane + sf, 64);
            yv += ax * Ws[sf * 4 + 0][lane];
            yv += ay * Ws[sf * 4 + 1][lane];
            yv += az * Ws[sf * 4 + 2][lane];
            yv += aw * Ws[sf * 4 + 3][lane];
        }
        y[(size_t)n * HID + lane] = yv;
        sv += yv;
        qv += yv * yv;
    }
    __shared__ float ls[4][64], lq[4][64];
    ls[wid][lane] = sv;
    lq[wid][lane] = qv;
    __syncthreads();
    if (wid == 0) {
        float S = ls[0][lane] + ls[1][lane] + ls[2][lane] + ls[3][lane];
        float Q = lq[0][lane] + lq[1][lane] + lq[2][lane] + lq[3][lane];
        float* rep = statsRep + (blockIdx.x & (NREP - 1)) * 128;
        atomicAdd(&rep[lane], S);
        atomicAdd(&rep[64 + lane], Q);
    }
}

// ---------------- GEMM 64x64 (BN finalize + relu fused; f16 message output) ------------

#define G64_ROWS 128
__global__ void gemm64_kernel(const float* __restrict__ hin, const float* __restrict__ W,
                              const float* __restrict__ sums, const float* __restrict__ sumsq,
                              const float* __restrict__ gamma, const float* __restrict__ beta,
                              const float* __restrict__ dis, _Float16* __restrict__ hout) {
    __shared__ float Ws[HID * HID];          // [k][f], f contiguous
    __shared__ float hs[G64_ROWS][HID + 1];  // +1 pad
    __shared__ float scb[64], shb[64];
    int t = threadIdx.x;
    int fg = t & 15;
    int rg = t >> 4;
    int base = blockIdx.x * G64_ROWS;

    if (t < 64) bn_coef(sums, sumsq, gamma, beta, t, scb[t], shb[t]);
    {
        const float4* W4 = (const float4*)W;
        float4* Ws4 = (float4*)Ws;
        for (int i = t; i < HID * HID / 4; i += 256) Ws4[i] = W4[i];
    }
    __syncthreads();
    {
        const float4* hin4 = (const float4*)hin;
        for (int i = t; i < G64_ROWS * 16; i += 256) {
            int r = i >> 4, c = i & 15;
            int n = base + r;
            float4 v = make_float4(0.f, 0.f, 0.f, 0.f);
            if (n < N_NODES) {
                float4 h = hin4[n * 16 + c];
                v.x = fmaxf(h.x * scb[c * 4 + 0] + shb[c * 4 + 0], 0.f);
                v.y = fmaxf(h.y * scb[c * 4 + 1] + shb[c * 4 + 1], 0.f);
                v.z = fmaxf(h.z * scb[c * 4 + 2] + shb[c * 4 + 2], 0.f);
                v.w = fmaxf(h.w * scb[c * 4 + 3] + shb[c * 4 + 3], 0.f);
            }
            hs[r][c * 4 + 0] = v.x;
            hs[r][c * 4 + 1] = v.y;
            hs[r][c * 4 + 2] = v.z;
            hs[r][c * 4 + 3] = v.w;
        }
    }
    __syncthreads();

    float4 acc[8];
#pragma unroll
    for (int r = 0; r < 8; r++) acc[r] = make_float4(0.f, 0.f, 0.f, 0.f);
    const float4* Ws4 = (const float4*)Ws;
    for (int k = 0; k < HID; k++) {
        float4 wk = Ws4[k * 16 + fg];
#pragma unroll
        for (int r = 0; r < 8; r++) {
            float h = hs[rg * 8 + r][k];
            acc[r].x += h * wk.x;
            acc[r].y += h * wk.y;
            acc[r].z += h * wk.z;
            acc[r].w += h * wk.w;
        }
    }
    half4* hout4 = (half4*)hout;
#pragma unroll
    for (int r = 0; r < 8; r++) {
        int n = base + rg * 8 + r;
        if (n < N_NODES) {
            float dsc = dis[n];
            half4 o;
            o.x = (_Float16)(acc[r].x * dsc);
            o.y = (_Float16)(acc[r].y * dsc);
            o.z = (_Float16)(acc[r].z * dsc);
            o.w = (_Float16)(acc[r].w * dsc);
            hout4[n * 16 + fg] = o;
        }
    }
}

// ---------------- Aggregation 64-dim: f16 rows (128B), 8 slots x half8, depth-2 --------

__global__ void aggregate_kernel(const half8* __restrict__ hwh, const int* __restrict__ csrOff,
                                 const int* __restrict__ csrSrc, const float* __restrict__ dis,
                                 const float* __restrict__ bias, float4* __restrict__ y4,
                                 float* __restrict__ statsRep) {
    const int lane = threadIdx.x & 63;
    const int wid = threadIdx.x >> 6;
    const int o = lane >> 3;  // edge slot 0..7
    const int c = lane & 7;   // half8 column within the 64-half row
    const int wave = blockIdx.x * 4 + wid;
    const int nwaves = gridDim.x * 4;

    const float4 bv0 = ((const float4*)bias)[c * 2];
    const float4 bv1 = ((const float4*)bias)[c * 2 + 1];
    float sa[8], qa[8];
#pragma unroll
    for (int j = 0; j < 8; j++) { sa[j] = 0.f; qa[j] = 0.f; }

    for (int n = wave; n < N_NODES; n += nwaves) {
        int beg = csrOff[n], end = csrOff[n + 1];
        float acc[8];
#pragma unroll
        for (int j = 0; j < 8; j++) acc[j] = 0.f;
        int e = beg + o;
        int i0 = (e < end) ? csrSrc[e] : N_NODES;
        int i1 = (e + 8 < end) ? csrSrc[e + 8] : N_NODES;
        while (e < end) {
            int j0 = i0, j1 = i1;
            e += 16;
            i0 = (e < end) ? csrSrc[e] : N_NODES;
            i1 = (e + 8 < end) ? csrSrc[e + 8] : N_NODES;
            half8 h0 = hwh[(size_t)j0 * 8 + c];
            half8 h1 = hwh[(size_t)j1 * 8 + c];
#pragma unroll
            for (int j = 0; j < 8; j++) acc[j] += (float)h0[j] + (float)h1[j];
        }
#pragma unroll
        for (int j = 0; j < 8; j++) {
            acc[j] += __shfl_xor(acc[j], 8, 64);
            acc[j] += __shfl_xor(acc[j], 16, 64);
            acc[j] += __shfl_xor(acc[j], 32, 64);
        }
        if (o == 0) {
            float d = dis[n];
            float val[8];
            val[0] = acc[0] * d + bv0.x; val[1] = acc[1] * d + bv0.y;
            val[2] = acc[2] * d + bv0.z; val[3] = acc[3] * d + bv0.w;
            val[4] = acc[4] * d + bv1.x; val[5] = acc[5] * d + bv1.y;
            val[6] = acc[6] * d + bv1.z; val[7] = acc[7] * d + bv1.w;
            y4[(size_t)n * 16 + c * 2] = make_float4(val[0], val[1], val[2], val[3]);
            y4[(size_t)n * 16 + c * 2 + 1] = make_float4(val[4], val[5], val[6], val[7]);
#pragma unroll
            for (int j = 0; j < 8; j++) { sa[j] += val[j]; qa[j] += val[j] * val[j]; }
        }
    }
    __shared__ float ls[4][64], lq[4][64];
    ls[wid][lane] = 0.f;
    lq[wid][lane] = 0.f;
    // same-wave program order: zeros land before the o==0 writes below
    if (o == 0) {
#pragma unroll
        for (int j = 0; j < 8; j++) { ls[wid][c * 8 + j] = sa[j]; lq[wid][c * 8 + j] = qa[j]; }
    }
    __syncthreads();
    if (wid == 0) {
        float S = ls[0][lane] + ls[1][lane] + ls[2][lane] + ls[3][lane];
        float Q = lq[0][lane] + lq[1][lane] + lq[2][lane] + lq[3][lane];
        float* rep = statsRep + (blockIdx.x & (NREP - 1)) * 128;
        atomicAdd(&rep[lane], S);
        atomicAdd(&rep[64 + lane], Q);
    }
}

// ---------------- Pool (BN finalize fused) + head ----------------

#define POOL_CHUNK 256
__global__ void pool_kernel(const float* __restrict__ y, const int* __restrict__ batch,
                            const float* __restrict__ sums, const float* __restrict__ sumsq,
                            const float* __restrict__ gamma, const float* __restrict__ beta,
                            float* __restrict__ pool, float* __restrict__ cnt) {
    int f = threadIdx.x & 63;
    int nl = threadIdx.x >> 6;
    float sc, sh;
    bn_coef(sums, sumsq, gamma, beta, f, sc, sh);
    int base = blockIdx.x * POOL_CHUNK;
    int endn = min(base + POOL_CHUNK, N_NODES);
    int g_cur = -1;
    float acc = 0.f;
    float c_acc = 0.f;
    for (int n = base + nl; n < endn; n += 4) {
        int g = batch[n];
        float v = fmaxf(y[n * HID + f] * sc + sh, 0.f);
        if (g != g_cur) {
            if (g_cur >= 0) {
                atomicAdd(&pool[g_cur * HID + f], acc);
                if (f == 0) atomicAdd(&cnt[g_cur], c_acc);
            }
            g_cur = g;
            acc = 0.f;
            c_acc = 0.f;
        }
        acc += v;
        c_acc += 1.f;
    }
    if (g_cur >= 0) {
        atomicAdd(&pool[g_cur * HID + f], acc);
        if (f == 0) atomicAdd(&cnt[g_cur], c_acc);
    }
}

__global__ void head_kernel(const float* __restrict__ pool, const float* __restrict__ cnt,
                            const float* __restrict__ Wc1, const float* __restrict__ bc1,
                            const float* __restrict__ Wc2, const float* __restrict__ bc2,
                            float* __restrict__ out) {
    int g = blockIdx.x;
    int f = threadIdx.x;  // 64 threads
    __shared__ float p[64], z[64];
    float c = fmaxf(cnt[g], 1.0f);
    p[f] = pool[g * HID + f] / c;
    __syncthreads();
    float acc = bc1[f];
    for (int k = 0; k < 64; k++) acc += p[k] * Wc1[k * 64 + f];
    z[f] = fmaxf(acc, 0.f);
    __syncthreads();
    if (f < 2) {
        float o = bc2[f];
        for (int k = 0; k < 64; k++) o += z[k] * Wc2[k * 2 + f];
        out[g * 2 + f] = o;
    }
}

// ---------------- launch ----------------

extern "C" void kernel_launch(void* const* d_in, const int* in_sizes, int n_in,
                              void* d_out, int out_size, void* d_ws, size_t ws_size,
                              hipStream_t stream) {
    const float* x      = (const float*)d_in[0];
    const int*   ei     = (const int*)d_in[1];
    const int*   batch  = (const int*)d_in[2];
    const float* bn_in_g = (const float*)d_in[3];
    const float* bn_in_b = (const float*)d_in[4];
    const float* W0 = (const float*)d_in[5];
    const float* b0 = (const float*)d_in[6];
    const float* g0 = (const float*)d_in[7];
    const float* be0 = (const float*)d_in[8];
    const float* W1 = (const float*)d_in[9];
    const float* b1 = (const float*)d_in[10];
    const float* g1 = (const float*)d_in[11];
    const float* be1 = (const float*)d_in[12];
    const float* W2 = (const float*)d_in[13];
    const float* b2 = (const float*)d_in[14];
    const float* g2 = (const float*)d_in[15];
    const float* be2 = (const float*)d_in[16];
    const float* Wc1 = (const float*)d_in[17];
    const float* bc1 = (const float*)d_in[18];
    const float* Wc2 = (const float*)d_in[19];
    const float* bc2 = (const float*)d_in[20];
    float* out = (float*)d_out;

    char* w = (char*)d_ws;
    size_t off = 0;
    auto take = [&](size_t bytes) {
        size_t r = off;
        off += (bytes + 255) & ~(size_t)255;
        return r;
    };
    // ---- zero region (one memset) ----
    float* stats    = (float*)(w + take(4 * 256 * 4));  // slot l: [sums 64][sumsq 64]
    float* statsRep = (float*)(w + take(3 * NREP * 128 * 4));  // replicated accumulators
    float* pool     = (float*)(w + take((size_t)N_GRAPHS * HID * 4));
    float* cnt      = (float*)(w + take((size_t)N_GRAPHS * 4));
    int* bucketCnt  = (int*)(w + take((size_t)NB_BUCKETS * 4));
    size_t zero_end = off;
    // ---- rest ----
    float* dis    = (float*)(w + take((size_t)N_NODES * 4));
    int* csrOff   = (int*)(w + take((size_t)(N_NODES + 1) * 4));
    int* csrSrc   = (int*)(w + take((size_t)(CSR_LEN + 64) * 4));
    _Float16* hwBuf = (_Float16*)(w + take((size_t)(N_NODES + 1) * HID * 2));  // f16 msgs +dummy
    float* yBuf   = (float*)(w + take((size_t)N_NODES * HID * 4));
    _Float16* msgBuf = (_Float16*)(w + take((size_t)(N_NODES + 1) * IN_DIM * 2));  // f16 16-dim
    int* regions  = (int*)hwBuf;   // alias: consumed by build_kernel before gemm64 writes
    (void)ws_size; (void)n_in; (void)in_sizes; (void)out_size;

    hipMemsetAsync(w, 0, zero_end, stream);

    const int nbBin  = (N_EDGES + BIN_TILE - 1) / BIN_TILE;  // 293
    const int nbPre  = ((N_NODES + 1) * 4 + 255) / 256;
    const int nbG64  = (N_NODES + G64_ROWS - 1) / G64_ROWS;
    const int nbAgg  = 4096;

    // CSR build (bucketed; self-loops folded in)
    bin_kernel<<<nbBin, 256, 0, stream>>>(ei, bucketCnt, regions);
    build_kernel<<<NB_BUCKETS, 256, 0, stream>>>(regions, bucketCnt, csrOff, csrSrc, dis);

    float* s0 = stats + 0 * 256;
    float* s1 = stats + 1 * 256;
    float* s2 = stats + 2 * 256;
    float* s3 = stats + 3 * 256;
    float* rep1 = statsRep + 0 * NREP * 128;
    float* rep2 = statsRep + 1 * NREP * 128;
    float* rep3 = statsRep + 2 * NREP * 128;

    // input BN stats (also zeroes hwBuf f16 dummy row)
    stats_x<<<256, 256, 0, stream>>>(x, s0, s0 + 64, hwBuf);

    // layer 0: premsg (f16) -> fused 16-dim aggregate + W0 GEMM
    premsg_kernel<<<nbPre, 256, 0, stream>>>(x, s0, s0 + 64, bn_in_g, bn_in_b, dis,
                                             (half4*)msgBuf);
    agg16_gemm0_kernel<<<nbAgg, 256, 0, stream>>>((const half4*)msgBuf, csrOff, csrSrc, dis,
                                                  W0, b0, yBuf, rep1);
    reduce_stats<<<1, 128, 0, stream>>>(rep1, s1);

    // layer 1
    gemm64_kernel<<<nbG64, 256, 0, stream>>>(yBuf, W1, s1, s1 + 64, g0, be0, dis, hwBuf);
    aggregate_kernel<<<nbAgg, 256, 0, stream>>>((const half8*)hwBuf, csrOff, csrSrc, dis, b1,
                                                (float4*)yBuf, rep2);
    reduce_stats<<<1, 128, 0, stream>>>(rep2, s2);

    // layer 2
    gemm64_kernel<<<nbG64, 256, 0, stream>>>(yBuf, W2, s2, s2 + 64, g1, be1, dis, hwBuf);
    aggregate_kernel<<<nbAgg, 256, 0, stream>>>((const half8*)hwBuf, csrOff, csrSrc, dis, b2,
                                                (float4*)yBuf, rep3);
    reduce_stats<<<1, 128, 0, stream>>>(rep3, s3);

    // pool + head
    const int nbPool = (N_NODES + POOL_CHUNK - 1) / POOL_CHUNK;
    pool_kernel<<<nbPool, 256, 0, stream>>>(yBuf, batch, s3, s3 + 64, g2, be2, pool, cnt);
    head_kernel<<<N_GRAPHS, 64, 0, stream>>>(pool, cnt, Wc1, bc1, Wc2, bc2, out);
}

// Round 11
// 319.999 us; speedup vs baseline: 1.7021x; 1.0771x over previous
//
#include <hip/hip_runtime.h>
#include <hip/hip_bf16.h>

#define N_NODES 100000
#define N_EDGES 1200000
#define N_GRAPHS 512
#define HID 64
#define IN_DIM 16
#define EPS 1e-5f

#define NB_BUCKETS 391   // ceil(N_NODES / BUCKET_SPAN)
#define BUCKET_SPAN 256  // dst >> 8
#define REGION 4096      // per-bucket region capacity (avg real fill ~3069)
#define BIN_TILE 4096    // edges per bin block
#define CSR_LEN (N_EDGES + N_NODES)  // self-loops folded in
#define NREP 64          // stats replicas (atomic de-contention)

typedef _Float16 half4 __attribute__((ext_vector_type(4)));
typedef _Float16 half8 __attribute__((ext_vector_type(8)));

// ---------------- CSR build (bucketed, LDS-built, self-loops included) ----------------

__global__ void bin_kernel(const int* __restrict__ ei, int* __restrict__ bucketCnt,
                           int* __restrict__ regions) {
    __shared__ int hist[NB_BUCKETS], basem[NB_BUCKETS], cur[NB_BUCKETS];
    int t = threadIdx.x;
    for (int i = t; i < NB_BUCKETS; i += 256) { hist[i] = 0; cur[i] = 0; }
    __syncthreads();
    int e0 = blockIdx.x * BIN_TILE;
    int srcs[16], dsts[16];
#pragma unroll
    for (int i = 0; i < 16; i++) {
        int e = e0 + t + i * 256;
        if (e < N_EDGES) {
            srcs[i] = ei[e];
            dsts[i] = ei[N_EDGES + e];
            atomicAdd(&hist[dsts[i] >> 8], 1);
        } else {
            dsts[i] = -1;
        }
    }
    __syncthreads();
    for (int i = t; i < NB_BUCKETS; i += 256) {
        int h = hist[i];
        basem[i] = h ? atomicAdd(&bucketCnt[i], h) : 0;
    }
    __syncthreads();
#pragma unroll
    for (int i = 0; i < 16; i++) {
        if (dsts[i] >= 0) {
            int b = dsts[i] >> 8;
            int pos = basem[b] + atomicAdd(&cur[b], 1);
            if (pos < REGION)
                regions[b * REGION + pos] = srcs[i] | ((dsts[i] & 255) << 17);
        }
    }
}

__global__ void build_kernel(const int* __restrict__ regions, const int* __restrict__ bucketCnt,
                             int* __restrict__ csrOff, int* __restrict__ csrSrc,
                             float* __restrict__ dis) {
    __shared__ int deg[256], off[256], cur[256];
    __shared__ int slice[REGION + 256];
    __shared__ int sTot, sBase;
    int b = blockIdx.x, t = threadIdx.x;
    {
        int s = 0;
        for (int i = t; i < NB_BUCKETS; i += 256)
            if (i < b) s += min(bucketCnt[i], REGION);
        deg[t] = s;
        __syncthreads();
        for (int k = 128; k > 0; k >>= 1) {
            if (t < k) deg[t] += deg[t + k];
            __syncthreads();
        }
        if (t == 0) sBase = deg[0] + b * BUCKET_SPAN;
        __syncthreads();
    }
    int bb = sBase;
    int cnt = min(bucketCnt[b], REGION);
    int nbase = b * BUCKET_SPAN;
    int n = nbase + t;
    bool valid = (n < N_NODES);
    deg[t] = valid ? 1 : 0;  // self loop
    __syncthreads();
    for (int i = t; i < cnt; i += 256) {
        int rec = regions[b * REGION + i];
        atomicAdd(&deg[rec >> 17], 1);
    }
    __syncthreads();
    int d = deg[t];
    off[t] = d;
    __syncthreads();
    for (int s = 1; s < 256; s <<= 1) {
        int v = (t >= s) ? off[t - s] : 0;
        __syncthreads();
        off[t] += v;
        __syncthreads();
    }
    int excl = off[t] - d;
    if (valid) {
        csrOff[n] = bb + excl;
        dis[n] = rsqrtf((float)d);
    }
    if (b == 0 && t == 0) csrOff[N_NODES] = CSR_LEN;
    if (t == 255) sTot = off[255];
    cur[t] = excl;
    __syncthreads();
    if (valid) {
        int pos = atomicAdd(&cur[t], 1);
        slice[pos] = n;
    }
    for (int i = t; i < cnt; i += 256) {
        int rec = regions[b * REGION + i];
        int pos = atomicAdd(&cur[rec >> 17], 1);
        slice[pos] = rec & 0x1FFFF;
    }
    __syncthreads();
    int tot = sTot;
    for (int i = t; i < tot; i += 256) csrSrc[bb + i] = slice[i];
}

// ---------------- BN statistics over x (also zeroes the f16 dummy gather row) -------

__global__ void stats_x(const float* __restrict__ x, float* __restrict__ sums,
                        float* __restrict__ sumsq, _Float16* __restrict__ hwBuf) {
    __shared__ float ls[16], lq[16];
    int t = threadIdx.x;
    if (blockIdx.x == 0 && t < 8)  // 64 halfs = 128 B = 8 x 16B
        ((float4*)(hwBuf + (size_t)N_NODES * HID))[t] = make_float4(0.f, 0.f, 0.f, 0.f);
    if (t < 16) { ls[t] = 0.f; lq[t] = 0.f; }
    __syncthreads();
    float s = 0.f, q = 0.f;
    const int total = N_NODES * IN_DIM;
    for (int i = blockIdx.x * blockDim.x + t; i < total; i += gridDim.x * blockDim.x) {
        float v = x[i];
        s += v; q += v * v;
    }
    int k = t & 15;
    atomicAdd(&ls[k], s);
    atomicAdd(&lq[k], q);
    __syncthreads();
    if (t < 16) { atomicAdd(&sums[t], ls[t]); atomicAdd(&sumsq[t], lq[t]); }
}

__device__ __forceinline__ void bn_coef(const float* sums, const float* sumsq,
                                        const float* gamma, const float* beta, int k,
                                        float& sc, float& sh) {
    const float invn = 1.0f / (float)N_NODES;
    float m = sums[k] * invn;
    float var = sumsq[k] * invn - m * m;
    float rs = rsqrtf(var + EPS);
    sc = gamma[k] * rs;
    sh = beta[k] - m * sc;
}

// fold NREP stats replicas ([NREP][128]) into canonical [sums 64 | sumsq 64]
__global__ void reduce_stats(const float* __restrict__ rep, float* __restrict__ outStats) {
    int j = threadIdx.x;  // 0..127
    float s = 0.f;
    for (int r = 0; r < NREP; r++) s += rep[r * 128 + j];
    outStats[j] = s;
}

// ---------------- Layer 0: premsg (f16) + fused aggregate16·W0 ----------------

// m[n] = BN(x[n]) * dis[n]  (16 halfs/row = 32 B); zeroes dummy row N_NODES
__global__ void premsg_kernel(const float* __restrict__ x, const float* __restrict__ sums,
                              const float* __restrict__ sumsq, const float* __restrict__ gamma,
                              const float* __restrict__ beta, const float* __restrict__ dis,
                              half4* __restrict__ m4) {
    __shared__ float sc16[16], sh16[16];
    int t = threadIdx.x;
    if (t < 16) bn_coef(sums, sumsq, gamma, beta, t, sc16[t], sh16[t]);
    __syncthreads();
    int idx = blockIdx.x * 256 + t;  // half4 index
    if (idx < (N_NODES + 1) * 4) {
        int n = idx >> 2, c = idx & 3;
        half4 o;
        o.x = (_Float16)0.f; o.y = (_Float16)0.f; o.z = (_Float16)0.f; o.w = (_Float16)0.f;
        if (n < N_NODES) {
            float4 h = ((const float4*)x)[idx];
            float d = dis[n];
            o.x = (_Float16)((h.x * sc16[c * 4 + 0] + sh16[c * 4 + 0]) * d);
            o.y = (_Float16)((h.y * sc16[c * 4 + 1] + sh16[c * 4 + 1]) * d);
            o.z = (_Float16)((h.z * sc16[c * 4 + 2] + sh16[c * 4 + 2]) * d);
            o.w = (_Float16)((h.w * sc16[c * 4 + 3] + sh16[c * 4 + 3]) * d);
        }
        m4[idx] = o;
    }
}

// 4 nodes per wave (16 lanes each: 4 slots x 4 half4-cols); W0 in registers.
// y[n,f] = (dis[n] * sum_{j in N(n)} m[j]) @ W0 + b0 ; BN stats into replicas.
__global__ void agg16_gemm0_kernel(const half4* __restrict__ m4, const int* __restrict__ csrOff,
                                   const int* __restrict__ csrSrc, const float* __restrict__ dis,
                                   const float* __restrict__ W, const float* __restrict__ bias,
                                   float* __restrict__ y, float* __restrict__ statsRep) {
    const int t = threadIdx.x;
    const int lane = t & 63;
    const int wid = t >> 6;
    const int g = lane >> 4;     // node subgroup 0..3
    const int s = lane & 15;     // lane within group
    const int fl = s & 3;        // half4 column (dims 4fl..4fl+3)
    const int q = s >> 2;        // edge slot 0..3
    const int wave = blockIdx.x * 4 + wid;
    const int nwaves = gridDim.x * 4;

    // W columns s, s+16, s+32, s+48 in registers
    float wreg[16][4];
#pragma unroll
    for (int k = 0; k < 16; k++) {
#pragma unroll
        for (int j = 0; j < 4; j++) wreg[k][j] = W[k * HID + s + 16 * j];
    }
    float bj[4];
#pragma unroll
    for (int j = 0; j < 4; j++) bj[j] = bias[s + 16 * j];
    float sv[4] = {0.f, 0.f, 0.f, 0.f}, qv[4] = {0.f, 0.f, 0.f, 0.f};

    for (int n0 = wave * 4; n0 < N_NODES; n0 += nwaves * 4) {
        int n = n0 + g;
        bool vn = (n < N_NODES);
        int beg = 0, end = 0;
        if (vn) { beg = csrOff[n]; end = csrOff[n + 1]; }
        float4 acc = make_float4(0.f, 0.f, 0.f, 0.f);
        int e = beg + q;
        int i0 = (e < end) ? csrSrc[e] : N_NODES;
        int i1 = (e + 4 < end) ? csrSrc[e + 4] : N_NODES;
        while (e < end) {
            int j0 = i0, j1 = i1;
            e += 8;
            i0 = (e < end) ? csrSrc[e] : N_NODES;
            i1 = (e + 4 < end) ? csrSrc[e + 4] : N_NODES;
            half4 v0 = m4[(size_t)j0 * 4 + fl];
            half4 v1 = m4[(size_t)j1 * 4 + fl];
            acc.x += (float)v0.x + (float)v1.x;
            acc.y += (float)v0.y + (float)v1.y;
            acc.z += (float)v0.z + (float)v1.z;
            acc.w += (float)v0.w + (float)v1.w;
        }
        // reduce over 4 slots (xor 4, 8) — one instruction serves all 4 node groups
        acc.x += __shfl_xor(acc.x, 4, 64);  acc.y += __shfl_xor(acc.y, 4, 64);
        acc.z += __shfl_xor(acc.z, 4, 64);  acc.w += __shfl_xor(acc.w, 4, 64);
        acc.x += __shfl_xor(acc.x, 8, 64);  acc.y += __shfl_xor(acc.y, 8, 64);
        acc.z += __shfl_xor(acc.z, 8, 64);  acc.w += __shfl_xor(acc.w, 8, 64);
        float d = vn ? dis[n] : 0.f;
        acc.x *= d; acc.y *= d; acc.z *= d; acc.w *= d;
        // each lane of group g holds agg[4fl..4fl+3]; broadcast within group + GEMM
        float yv0 = bj[0], yv1 = bj[1], yv2 = bj[2], yv3 = bj[3];
        const int gbase = lane & 48;  // 16*g
#pragma unroll
        for (int k = 0; k < 16; k++) {
            float comp = ((k & 3) == 0) ? acc.x : ((k & 3) == 1) ? acc.y
                        : ((k & 3) == 2) ? acc.z : acc.w;
            float a = __shfl(comp, gbase + (k >> 2), 64);
            yv0 += a * wreg[k][0];
            yv1 += a * wreg[k][1];
            yv2 += a * wreg[k][2];
            yv3 += a * wreg[k][3];
        }
        if (vn) {
            float* yr = y + (size_t)n * HID;
            yr[s] = yv0; yr[s + 16] = yv1; yr[s + 32] = yv2; yr[s + 48] = yv3;
            sv[0] += yv0; qv[0] += yv0 * yv0;
            sv[1] += yv1; qv[1] += yv1 * yv1;
            sv[2] += yv2; qv[2] += yv2 * yv2;
            sv[3] += yv3; qv[3] += yv3 * yv3;
        }
    }
    // stats: node-groups cover identical feature sets -> reduce over g (xor 16, 32)
#pragma unroll
    for (int j = 0; j < 4; j++) {
        sv[j] += __shfl_xor(sv[j], 16, 64); sv[j] += __shfl_xor(sv[j], 32, 64);
        qv[j] += __shfl_xor(qv[j], 16, 64); qv[j] += __shfl_xor(qv[j], 32, 64);
    }
    __shared__ float ls[4][64], lq[4][64];
    if (g == 0) {
#pragma unroll
        for (int j = 0; j < 4; j++) { ls[wid][s + 16 * j] = sv[j]; lq[wid][s + 16 * j] = qv[j]; }
    }
    __syncthreads();
    if (wid == 0) {
        float S = ls[0][lane] + ls[1][lane] + ls[2][lane] + ls[3][lane];
        float Q = lq[0][lane] + lq[1][lane] + lq[2][lane] + lq[3][lane];
        float* rep = statsRep + (blockIdx.x & (NREP - 1)) * 128;
        atomicAdd(&rep[lane], S);
        atomicAdd(&rep[64 + lane], Q);
    }
}

// ---------------- GEMM 64x64 (BN finalize + relu fused; f16 message output) ------------

#define G64_ROWS 128
__global__ void gemm64_kernel(const float* __restrict__ hin, const float* __restrict__ W,
                              const float* __restrict__ sums, const float* __restrict__ sumsq,
                              const float* __restrict__ gamma, const float* __restrict__ beta,
                              const float* __restrict__ dis, _Float16* __restrict__ hout) {
    __shared__ float Ws[HID * HID];          // [k][f], f contiguous
    __shared__ float hs[G64_ROWS][HID + 1];  // +1 pad
    __shared__ float scb[64], shb[64];
    int t = threadIdx.x;
    int fg = t & 15;
    int rg = t >> 4;
    int base = blockIdx.x * G64_ROWS;

    if (t < 64) bn_coef(sums, sumsq, gamma, beta, t, scb[t], shb[t]);
    {
        const float4* W4 = (const float4*)W;
        float4* Ws4 = (float4*)Ws;
        for (int i = t; i < HID * HID / 4; i += 256) Ws4[i] = W4[i];
    }
    __syncthreads();
    {
        const float4* hin4 = (const float4*)hin;
        for (int i = t; i < G64_ROWS * 16; i += 256) {
            int r = i >> 4, c = i & 15;
            int n = base + r;
            float4 v = make_float4(0.f, 0.f, 0.f, 0.f);
            if (n < N_NODES) {
                float4 h = hin4[n * 16 + c];
                v.x = fmaxf(h.x * scb[c * 4 + 0] + shb[c * 4 + 0], 0.f);
                v.y = fmaxf(h.y * scb[c * 4 + 1] + shb[c * 4 + 1], 0.f);
                v.z = fmaxf(h.z * scb[c * 4 + 2] + shb[c * 4 + 2], 0.f);
                v.w = fmaxf(h.w * scb[c * 4 + 3] + shb[c * 4 + 3], 0.f);
            }
            hs[r][c * 4 + 0] = v.x;
            hs[r][c * 4 + 1] = v.y;
            hs[r][c * 4 + 2] = v.z;
            hs[r][c * 4 + 3] = v.w;
        }
    }
    __syncthreads();

    float4 acc[8];
#pragma unroll
    for (int r = 0; r < 8; r++) acc[r] = make_float4(0.f, 0.f, 0.f, 0.f);
    const float4* Ws4 = (const float4*)Ws;
    for (int k = 0; k < HID; k++) {
        float4 wk = Ws4[k * 16 + fg];
#pragma unroll
        for (int r = 0; r < 8; r++) {
            float h = hs[rg * 8 + r][k];
            acc[r].x += h * wk.x;
            acc[r].y += h * wk.y;
            acc[r].z += h * wk.z;
            acc[r].w += h * wk.w;
        }
    }
    half4* hout4 = (half4*)hout;
#pragma unroll
    for (int r = 0; r < 8; r++) {
        int n = base + rg * 8 + r;
        if (n < N_NODES) {
            float dsc = dis[n];
            half4 o;
            o.x = (_Float16)(acc[r].x * dsc);
            o.y = (_Float16)(acc[r].y * dsc);
            o.z = (_Float16)(acc[r].z * dsc);
            o.w = (_Float16)(acc[r].w * dsc);
            hout4[n * 16 + fg] = o;
        }
    }
}

// ---------------- Aggregation 64-dim: 2 nodes/wave (4 slots x 8 half8-cols) ------------

__global__ void aggregate_kernel(const half8* __restrict__ hwh, const int* __restrict__ csrOff,
                                 const int* __restrict__ csrSrc, const float* __restrict__ dis,
                                 const float* __restrict__ bias, float4* __restrict__ y4,
                                 float* __restrict__ statsRep) {
    const int lane = threadIdx.x & 63;
    const int wid = threadIdx.x >> 6;
    const int g = lane >> 5;  // node subgroup 0..1
    const int s = lane & 31;
    const int c = s & 7;      // half8 column within the 64-half row
    const int o = s >> 3;     // edge slot 0..3
    const int wave = blockIdx.x * 4 + wid;
    const int nwaves = gridDim.x * 4;

    const float4 bv0 = ((const float4*)bias)[c * 2];
    const float4 bv1 = ((const float4*)bias)[c * 2 + 1];
    float sa[8], qa[8];
#pragma unroll
    for (int j = 0; j < 8; j++) { sa[j] = 0.f; qa[j] = 0.f; }

    for (int n0 = wave * 2; n0 < N_NODES; n0 += nwaves * 2) {
        int n = n0 + g;
        bool vn = (n < N_NODES);
        int beg = 0, end = 0;
        if (vn) { beg = csrOff[n]; end = csrOff[n + 1]; }
        float acc[8];
#pragma unroll
        for (int j = 0; j < 8; j++) acc[j] = 0.f;
        int e = beg + o;
        int i0 = (e < end) ? csrSrc[e] : N_NODES;
        int i1 = (e + 4 < end) ? csrSrc[e + 4] : N_NODES;
        while (e < end) {
            int j0 = i0, j1 = i1;
            e += 8;
            i0 = (e < end) ? csrSrc[e] : N_NODES;
            i1 = (e + 4 < end) ? csrSrc[e + 4] : N_NODES;
            half8 h0 = hwh[(size_t)j0 * 8 + c];
            half8 h1 = hwh[(size_t)j1 * 8 + c];
#pragma unroll
            for (int j = 0; j < 8; j++) acc[j] += (float)h0[j] + (float)h1[j];
        }
        // reduce over 4 slots (xor 8, 16) — one instruction serves both node groups
#pragma unroll
        for (int j = 0; j < 8; j++) {
            acc[j] += __shfl_xor(acc[j], 8, 64);
            acc[j] += __shfl_xor(acc[j], 16, 64);
        }
        if (o == 0 && vn) {
            float d = dis[n];
            float val[8];
            val[0] = acc[0] * d + bv0.x; val[1] = acc[1] * d + bv0.y;
            val[2] = acc[2] * d + bv0.z; val[3] = acc[3] * d + bv0.w;
            val[4] = acc[4] * d + bv1.x; val[5] = acc[5] * d + bv1.y;
            val[6] = acc[6] * d + bv1.z; val[7] = acc[7] * d + bv1.w;
            y4[(size_t)n * 16 + c * 2] = make_float4(val[0], val[1], val[2], val[3]);
            y4[(size_t)n * 16 + c * 2 + 1] = make_float4(val[4], val[5], val[6], val[7]);
#pragma unroll
            for (int j = 0; j < 8; j++) { sa[j] += val[j]; qa[j] += val[j] * val[j]; }
        }
    }
    // stats: both node-groups cover identical feature sets -> reduce over g (xor 32)
#pragma unroll
    for (int j = 0; j < 8; j++) {
        sa[j] += __shfl_xor(sa[j], 32, 64);
        qa[j] += __shfl_xor(qa[j], 32, 64);
    }
    __shared__ float ls[4][64], lq[4][64];
    ls[wid][lane] = 0.f;
    lq[wid][lane] = 0.f;
    // same-wave program order: zeros land before the lane<8 writes below
    if (lane < 8) {  // o==0 && g==0; c == lane
#pragma unroll
        for (int j = 0; j < 8; j++) { ls[wid][lane * 8 + j] = sa[j]; lq[wid][lane * 8 + j] = qa[j]; }
    }
    __syncthreads();
    if (wid == 0) {
        float S = ls[0][lane] + ls[1][lane] + ls[2][lane] + ls[3][lane];
        float Q = lq[0][lane] + lq[1][lane] + lq[2][lane] + lq[3][lane];
        float* rep = statsRep + (blockIdx.x & (NREP - 1)) * 128;
        atomicAdd(&rep[lane], S);
        atomicAdd(&rep[64 + lane], Q);
    }
}

// ---------------- Pool (BN finalize fused) + head ----------------

#define POOL_CHUNK 256
__global__ void pool_kernel(const float* __restrict__ y, const int* __restrict__ batch,
                            const float* __restrict__ sums, const float* __restrict__ sumsq,
                            const float* __restrict__ gamma, const float* __restrict__ beta,
                            float* __restrict__ pool, float* __restrict__ cnt) {
    int f = threadIdx.x & 63;
    int nl = threadIdx.x >> 6;
    float sc, sh;
    bn_coef(sums, sumsq, gamma, beta, f, sc, sh);
    int base = blockIdx.x * POOL_CHUNK;
    int endn = min(base + POOL_CHUNK, N_NODES);
    int g_cur = -1;
    float acc = 0.f;
    float c_acc = 0.f;
    for (int n = base + nl; n < endn; n += 4) {
        int g = batch[n];
        float v = fmaxf(y[n * HID + f] * sc + sh, 0.f);
        if (g != g_cur) {
            if (g_cur >= 0) {
                atomicAdd(&pool[g_cur * HID + f], acc);
                if (f == 0) atomicAdd(&cnt[g_cur], c_acc);
            }
            g_cur = g;
            acc = 0.f;
            c_acc = 0.f;
        }
        acc += v;
        c_acc += 1.f;
    }
    if (g_cur >= 0) {
        atomicAdd(&pool[g_cur * HID + f], acc);
        if (f == 0) atomicAdd(&cnt[g_cur], c_acc);
    }
}

__global__ void head_kernel(const float* __restrict__ pool, const float* __restrict__ cnt,
                            const float* __restrict__ Wc1, const float* __restrict__ bc1,
                            const float* __restrict__ Wc2, const float* __restrict__ bc2,
                            float* __restrict__ out) {
    int g = blockIdx.x;
    int f = threadIdx.x;  // 64 threads
    __shared__ float p[64], z[64];
    float c = fmaxf(cnt[g], 1.0f);
    p[f] = pool[g * HID + f] / c;
    __syncthreads();
    float acc = bc1[f];
    for (int k = 0; k < 64; k++) acc += p[k] * Wc1[k * 64 + f];
    z[f] = fmaxf(acc, 0.f);
    __syncthreads();
    if (f < 2) {
        float o = bc2[f];
        for (int k = 0; k < 64; k++) o += z[k] * Wc2[k * 2 + f];
        out[g * 2 + f] = o;
    }
}

// ---------------- launch ----------------

extern "C" void kernel_launch(void* const* d_in, const int* in_sizes, int n_in,
                              void* d_out, int out_size, void* d_ws, size_t ws_size,
                              hipStream_t stream) {
    const float* x      = (const float*)d_in[0];
    const int*   ei     = (const int*)d_in[1];
    const int*   batch  = (const int*)d_in[2];
    const float* bn_in_g = (const float*)d_in[3];
    const float* bn_in_b = (const float*)d_in[4];
    const float* W0 = (const float*)d_in[5];
    const float* b0 = (const float*)d_in[6];
    const float* g0 = (const float*)d_in[7];
    const float* be0 = (const float*)d_in[8];
    const float* W1 = (const float*)d_in[9];
    const float* b1 = (const float*)d_in[10];
    const float* g1 = (const float*)d_in[11];
    const float* be1 = (const float*)d_in[12];
    const float* W2 = (const float*)d_in[13];
    const float* b2 = (const float*)d_in[14];
    const float* g2 = (const float*)d_in[15];
    const float* be2 = (const float*)d_in[16];
    const float* Wc1 = (const float*)d_in[17];
    const float* bc1 = (const float*)d_in[18];
    const float* Wc2 = (const float*)d_in[19];
    const float* bc2 = (const float*)d_in[20];
    float* out = (float*)d_out;

    char* w = (char*)d_ws;
    size_t off = 0;
    auto take = [&](size_t bytes) {
        size_t r = off;
        off += (bytes + 255) & ~(size_t)255;
        return r;
    };
    // ---- zero region (one memset) ----
    float* stats    = (float*)(w + take(4 * 256 * 4));  // slot l: [sums 64][sumsq 64]
    float* statsRep = (float*)(w + take(3 * NREP * 128 * 4));  // replicated accumulators
    float* pool     = (float*)(w + take((size_t)N_GRAPHS * HID * 4));
    float* cnt      = (float*)(w + take((size_t)N_GRAPHS * 4));
    int* bucketCnt  = (int*)(w + take((size_t)NB_BUCKETS * 4));
    size_t zero_end = off;
    // ---- rest ----
    float* dis    = (float*)(w + take((size_t)N_NODES * 4));
    int* csrOff   = (int*)(w + take((size_t)(N_NODES + 1) * 4));
    int* csrSrc   = (int*)(w + take((size_t)(CSR_LEN + 64) * 4));
    _Float16* hwBuf = (_Float16*)(w + take((size_t)(N_NODES + 1) * HID * 2));  // f16 msgs +dummy
    float* yBuf   = (float*)(w + take((size_t)N_NODES * HID * 4));
    _Float16* msgBuf = (_Float16*)(w + take((size_t)(N_NODES + 1) * IN_DIM * 2));  // f16 16-dim
    int* regions  = (int*)hwBuf;   // alias: consumed by build_kernel before gemm64 writes
    (void)ws_size; (void)n_in; (void)in_sizes; (void)out_size;

    hipMemsetAsync(w, 0, zero_end, stream);

    const int nbBin   = (N_EDGES + BIN_TILE - 1) / BIN_TILE;  // 293
    const int nbPre   = ((N_NODES + 1) * 4 + 255) / 256;
    const int nbG64   = (N_NODES + G64_ROWS - 1) / G64_ROWS;
    const int nbAgg16 = (N_NODES + 16 * 4 - 1) / (16 * 4);  // 4 waves x 4 nodes per block
    const int nbAgg64 = (N_NODES + 8 * 4 - 1) / (8 * 4);    // 4 waves x 2 nodes per block

    // CSR build (bucketed; self-loops folded in)
    bin_kernel<<<nbBin, 256, 0, stream>>>(ei, bucketCnt, regions);
    build_kernel<<<NB_BUCKETS, 256, 0, stream>>>(regions, bucketCnt, csrOff, csrSrc, dis);

    float* s0 = stats + 0 * 256;
    float* s1 = stats + 1 * 256;
    float* s2 = stats + 2 * 256;
    float* s3 = stats + 3 * 256;
    float* rep1 = statsRep + 0 * NREP * 128;
    float* rep2 = statsRep + 1 * NREP * 128;
    float* rep3 = statsRep + 2 * NREP * 128;

    // input BN stats (also zeroes hwBuf f16 dummy row)
    stats_x<<<256, 256, 0, stream>>>(x, s0, s0 + 64, hwBuf);

    // layer 0: premsg (f16) -> fused 16-dim aggregate + W0 GEMM
    premsg_kernel<<<nbPre, 256, 0, stream>>>(x, s0, s0 + 64, bn_in_g, bn_in_b, dis,
                                             (half4*)msgBuf);
    agg16_gemm0_kernel<<<nbAgg16, 256, 0, stream>>>((const half4*)msgBuf, csrOff, csrSrc, dis,
                                                    W0, b0, yBuf, rep1);
    reduce_stats<<<1, 128, 0, stream>>>(rep1, s1);

    // layer 1
    gemm64_kernel<<<nbG64, 256, 0, stream>>>(yBuf, W1, s1, s1 + 64, g0, be0, dis, hwBuf);
    aggregate_kernel<<<nbAgg64, 256, 0, stream>>>((const half8*)hwBuf, csrOff, csrSrc, dis, b1,
                                                  (float4*)yBuf, rep2);
    reduce_stats<<<1, 128, 0, stream>>>(rep2, s2);

    // layer 2
    gemm64_kernel<<<nbG64, 256, 0, stream>>>(yBuf, W2, s2, s2 + 64, g1, be1, dis, hwBuf);
    aggregate_kernel<<<nbAgg64, 256, 0, stream>>>((const half8*)hwBuf, csrOff, csrSrc, dis, b2,
                                                  (float4*)yBuf, rep3);
    reduce_stats<<<1, 128, 0, stream>>>(rep3, s3);

    // pool + head
    const int nbPool = (N_NODES + POOL_CHUNK - 1) / POOL_CHUNK;
    pool_kernel<<<nbPool, 256, 0, stream>>>(yBuf, batch, s3, s3 + 64, g2, be2, pool, cnt);
    head_kernel<<<N_GRAPHS, 64, 0, stream>>>(pool, cnt, Wc1, bc1, Wc2, bc2, out);
}

// Round 12
// 311.686 us; speedup vs baseline: 1.7475x; 1.0267x over previous
//
#include <hip/hip_runtime.h>
#include <hip/hip_bf16.h>

#define N_NODES 100000
#define N_EDGES 1200000
#define N_GRAPHS 512
#define HID 64
#define IN_DIM 16
#define EPS 1e-5f

#define NB_BUCKETS 391   // ceil(N_NODES / BUCKET_SPAN)
#define BUCKET_SPAN 256  // dst >> 8
#define REGION 4096      // per-bucket region capacity (avg real fill ~3069)
#define BIN_TILE 4096    // edges per bin block
#define CSR_LEN (N_EDGES + N_NODES)  // self-loops folded in
#define NREP 64          // stats replicas (atomic de-contention)

typedef _Float16 half4 __attribute__((ext_vector_type(4)));
typedef _Float16 half8 __attribute__((ext_vector_type(8)));

// ---------------- CSR build (bucketed, LDS-built, self-loops included) ----------------

__global__ void bin_kernel(const int* __restrict__ ei, int* __restrict__ bucketCnt,
                           int* __restrict__ regions) {
    __shared__ int hist[NB_BUCKETS], basem[NB_BUCKETS], cur[NB_BUCKETS];
    int t = threadIdx.x;
    for (int i = t; i < NB_BUCKETS; i += 256) { hist[i] = 0; cur[i] = 0; }
    __syncthreads();
    const int4* ei4s = (const int4*)ei;
    const int4* ei4d = (const int4*)(ei + N_EDGES);
    int srcs[16], dsts[16];
#pragma unroll
    for (int i = 0; i < 4; i++) {
        int idx4 = blockIdx.x * (BIN_TILE / 4) + t + i * 256;
        if (idx4 * 4 < N_EDGES) {
            int4 s4 = ei4s[idx4];
            int4 d4 = ei4d[idx4];
            srcs[i * 4 + 0] = s4.x; dsts[i * 4 + 0] = d4.x;
            srcs[i * 4 + 1] = s4.y; dsts[i * 4 + 1] = d4.y;
            srcs[i * 4 + 2] = s4.z; dsts[i * 4 + 2] = d4.z;
            srcs[i * 4 + 3] = s4.w; dsts[i * 4 + 3] = d4.w;
            atomicAdd(&hist[d4.x >> 8], 1);
            atomicAdd(&hist[d4.y >> 8], 1);
            atomicAdd(&hist[d4.z >> 8], 1);
            atomicAdd(&hist[d4.w >> 8], 1);
        } else {
            dsts[i * 4 + 0] = -1; dsts[i * 4 + 1] = -1;
            dsts[i * 4 + 2] = -1; dsts[i * 4 + 3] = -1;
        }
    }
    __syncthreads();
    for (int i = t; i < NB_BUCKETS; i += 256) {
        int h = hist[i];
        basem[i] = h ? atomicAdd(&bucketCnt[i], h) : 0;
    }
    __syncthreads();
#pragma unroll
    for (int i = 0; i < 16; i++) {
        if (dsts[i] >= 0) {
            int b = dsts[i] >> 8;
            int pos = basem[b] + atomicAdd(&cur[b], 1);
            if (pos < REGION)
                regions[b * REGION + pos] = srcs[i] | ((dsts[i] & 255) << 17);
        }
    }
}

__global__ void build_kernel(const int* __restrict__ regions, const int* __restrict__ bucketCnt,
                             int* __restrict__ csrOff, int* __restrict__ csrSrc,
                             float* __restrict__ dis) {
    __shared__ int deg[256], off[256], cur[256];
    __shared__ int slice[REGION + 256];
    __shared__ int sTot, sBase;
    int b = blockIdx.x, t = threadIdx.x;
    {
        int s = 0;
        for (int i = t; i < NB_BUCKETS; i += 256)
            if (i < b) s += min(bucketCnt[i], REGION);
        deg[t] = s;
        __syncthreads();
        for (int k = 128; k > 0; k >>= 1) {
            if (t < k) deg[t] += deg[t + k];
            __syncthreads();
        }
        if (t == 0) sBase = deg[0] + b * BUCKET_SPAN;
        __syncthreads();
    }
    int bb = sBase;
    int cnt = min(bucketCnt[b], REGION);
    int nbase = b * BUCKET_SPAN;
    int n = nbase + t;
    bool valid = (n < N_NODES);
    deg[t] = valid ? 1 : 0;  // self loop
    __syncthreads();
    for (int i = t; i < cnt; i += 256) {
        int rec = regions[b * REGION + i];
        atomicAdd(&deg[rec >> 17], 1);
    }
    __syncthreads();
    int d = deg[t];
    off[t] = d;
    __syncthreads();
    for (int s = 1; s < 256; s <<= 1) {
        int v = (t >= s) ? off[t - s] : 0;
        __syncthreads();
        off[t] += v;
        __syncthreads();
    }
    int excl = off[t] - d;
    if (valid) {
        csrOff[n] = bb + excl;
        dis[n] = rsqrtf((float)d);
    }
    if (b == 0 && t == 0) csrOff[N_NODES] = CSR_LEN;
    if (t == 255) sTot = off[255];
    cur[t] = excl;
    __syncthreads();
    if (valid) {
        int pos = atomicAdd(&cur[t], 1);
        slice[pos] = n;
    }
    for (int i = t; i < cnt; i += 256) {
        int rec = regions[b * REGION + i];
        int pos = atomicAdd(&cur[rec >> 17], 1);
        slice[pos] = rec & 0x1FFFF;
    }
    __syncthreads();
    int tot = sTot;
    for (int i = t; i < tot; i += 256) csrSrc[bb + i] = slice[i];
}

// ---------------- BN statistics over x (also zeroes the f16 dummy gather row) -------

__global__ void stats_x(const float* __restrict__ x, float* __restrict__ sums,
                        float* __restrict__ sumsq, _Float16* __restrict__ hwBuf) {
    __shared__ float ls[16], lq[16];
    int t = threadIdx.x;
    if (blockIdx.x == 0 && t < 8)  // 64 halfs = 128 B = 8 x 16B
        ((float4*)(hwBuf + (size_t)N_NODES * HID))[t] = make_float4(0.f, 0.f, 0.f, 0.f);
    if (t < 16) { ls[t] = 0.f; lq[t] = 0.f; }
    __syncthreads();
    float s = 0.f, q = 0.f;
    const int total = N_NODES * IN_DIM;
    for (int i = blockIdx.x * blockDim.x + t; i < total; i += gridDim.x * blockDim.x) {
        float v = x[i];
        s += v; q += v * v;
    }
    int k = t & 15;
    atomicAdd(&ls[k], s);
    atomicAdd(&lq[k], q);
    __syncthreads();
    if (t < 16) { atomicAdd(&sums[t], ls[t]); atomicAdd(&sumsq[t], lq[t]); }
}

__device__ __forceinline__ void bn_coef(const float* sums, const float* sumsq,
                                        const float* gamma, const float* beta, int k,
                                        float& sc, float& sh) {
    const float invn = 1.0f / (float)N_NODES;
    float m = sums[k] * invn;
    float var = sumsq[k] * invn - m * m;
    float rs = rsqrtf(var + EPS);
    sc = gamma[k] * rs;
    sh = beta[k] - m * sc;
}

// reduce replicas + bn finalize for feature k (k < 64)
__device__ __forceinline__ void bn_coef_rep(const float* rep, const float* gamma,
                                            const float* beta, int k, float& sc, float& sh) {
    float S = 0.f, Q = 0.f;
    for (int r = 0; r < NREP; r++) { S += rep[r * 128 + k]; Q += rep[r * 128 + 64 + k]; }
    const float invn = 1.0f / (float)N_NODES;
    float m = S * invn;
    float var = Q * invn - m * m;
    float rs = rsqrtf(var + EPS);
    sc = gamma[k] * rs;
    sh = beta[k] - m * sc;
}

// ---------------- Layer 0: premsg (f16) + fused aggregate16·W0 ----------------

// m[n] = BN(x[n]) * dis[n]  (16 halfs/row = 32 B); zeroes dummy row N_NODES
__global__ void premsg_kernel(const float* __restrict__ x, const float* __restrict__ sums,
                              const float* __restrict__ sumsq, const float* __restrict__ gamma,
                              const float* __restrict__ beta, const float* __restrict__ dis,
                              half4* __restrict__ m4) {
    __shared__ float sc16[16], sh16[16];
    int t = threadIdx.x;
    if (t < 16) bn_coef(sums, sumsq, gamma, beta, t, sc16[t], sh16[t]);
    __syncthreads();
    int idx = blockIdx.x * 256 + t;  // half4 index
    if (idx < (N_NODES + 1) * 4) {
        int n = idx >> 2, c = idx & 3;
        half4 o;
        o.x = (_Float16)0.f; o.y = (_Float16)0.f; o.z = (_Float16)0.f; o.w = (_Float16)0.f;
        if (n < N_NODES) {
            float4 h = ((const float4*)x)[idx];
            float d = dis[n];
            o.x = (_Float16)((h.x * sc16[c * 4 + 0] + sh16[c * 4 + 0]) * d);
            o.y = (_Float16)((h.y * sc16[c * 4 + 1] + sh16[c * 4 + 1]) * d);
            o.z = (_Float16)((h.z * sc16[c * 4 + 2] + sh16[c * 4 + 2]) * d);
            o.w = (_Float16)((h.w * sc16[c * 4 + 3] + sh16[c * 4 + 3]) * d);
        }
        m4[idx] = o;
    }
}

// 4 nodes per wave (16 lanes each); W0 in registers; f16 y output.
__global__ void agg16_gemm0_kernel(const half4* __restrict__ m4, const int* __restrict__ csrOff,
                                   const int* __restrict__ csrSrc, const float* __restrict__ dis,
                                   const float* __restrict__ W, const float* __restrict__ bias,
                                   _Float16* __restrict__ y, float* __restrict__ statsRep) {
    const int t = threadIdx.x;
    const int lane = t & 63;
    const int wid = t >> 6;
    const int g = lane >> 4;     // node subgroup 0..3
    const int s = lane & 15;     // lane within group
    const int fl = s & 3;        // half4 column (dims 4fl..4fl+3)
    const int q = s >> 2;        // edge slot 0..3
    const int wave = blockIdx.x * 4 + wid;
    const int nwaves = gridDim.x * 4;

    float wreg[16][4];
#pragma unroll
    for (int k = 0; k < 16; k++) {
#pragma unroll
        for (int j = 0; j < 4; j++) wreg[k][j] = W[k * HID + s + 16 * j];
    }
    float bj[4];
#pragma unroll
    for (int j = 0; j < 4; j++) bj[j] = bias[s + 16 * j];
    float sv[4] = {0.f, 0.f, 0.f, 0.f}, qv[4] = {0.f, 0.f, 0.f, 0.f};

    for (int n0 = wave * 4; n0 < N_NODES; n0 += nwaves * 4) {
        int n = n0 + g;
        bool vn = (n < N_NODES);
        int beg = 0, end = 0;
        if (vn) { beg = csrOff[n]; end = csrOff[n + 1]; }
        float4 acc = make_float4(0.f, 0.f, 0.f, 0.f);
        int e = beg + q;
        int i0 = (e < end) ? csrSrc[e] : N_NODES;
        int i1 = (e + 4 < end) ? csrSrc[e + 4] : N_NODES;
        while (e < end) {
            int j0 = i0, j1 = i1;
            e += 8;
            i0 = (e < end) ? csrSrc[e] : N_NODES;
            i1 = (e + 4 < end) ? csrSrc[e + 4] : N_NODES;
            half4 v0 = m4[(size_t)j0 * 4 + fl];
            half4 v1 = m4[(size_t)j1 * 4 + fl];
            acc.x += (float)v0.x + (float)v1.x;
            acc.y += (float)v0.y + (float)v1.y;
            acc.z += (float)v0.z + (float)v1.z;
            acc.w += (float)v0.w + (float)v1.w;
        }
        acc.x += __shfl_xor(acc.x, 4, 64);  acc.y += __shfl_xor(acc.y, 4, 64);
        acc.z += __shfl_xor(acc.z, 4, 64);  acc.w += __shfl_xor(acc.w, 4, 64);
        acc.x += __shfl_xor(acc.x, 8, 64);  acc.y += __shfl_xor(acc.y, 8, 64);
        acc.z += __shfl_xor(acc.z, 8, 64);  acc.w += __shfl_xor(acc.w, 8, 64);
        float d = vn ? dis[n] : 0.f;
        acc.x *= d; acc.y *= d; acc.z *= d; acc.w *= d;
        float yv0 = bj[0], yv1 = bj[1], yv2 = bj[2], yv3 = bj[3];
        const int gbase = lane & 48;  // 16*g
#pragma unroll
        for (int k = 0; k < 16; k++) {
            float comp = ((k & 3) == 0) ? acc.x : ((k & 3) == 1) ? acc.y
                        : ((k & 3) == 2) ? acc.z : acc.w;
            float a = __shfl(comp, gbase + (k >> 2), 64);
            yv0 += a * wreg[k][0];
            yv1 += a * wreg[k][1];
            yv2 += a * wreg[k][2];
            yv3 += a * wreg[k][3];
        }
        if (vn) {
            _Float16* yr = y + (size_t)n * HID;
            yr[s] = (_Float16)yv0; yr[s + 16] = (_Float16)yv1;
            yr[s + 32] = (_Float16)yv2; yr[s + 48] = (_Float16)yv3;
            sv[0] += yv0; qv[0] += yv0 * yv0;
            sv[1] += yv1; qv[1] += yv1 * yv1;
            sv[2] += yv2; qv[2] += yv2 * yv2;
            sv[3] += yv3; qv[3] += yv3 * yv3;
        }
    }
#pragma unroll
    for (int j = 0; j < 4; j++) {
        sv[j] += __shfl_xor(sv[j], 16, 64); sv[j] += __shfl_xor(sv[j], 32, 64);
        qv[j] += __shfl_xor(qv[j], 16, 64); qv[j] += __shfl_xor(qv[j], 32, 64);
    }
    __shared__ float ls[4][64], lq[4][64];
    if (g == 0) {
#pragma unroll
        for (int j = 0; j < 4; j++) { ls[wid][s + 16 * j] = sv[j]; lq[wid][s + 16 * j] = qv[j]; }
    }
    __syncthreads();
    if (wid == 0) {
        float S = ls[0][lane] + ls[1][lane] + ls[2][lane] + ls[3][lane];
        float Q = lq[0][lane] + lq[1][lane] + lq[2][lane] + lq[3][lane];
        float* rep = statsRep + (blockIdx.x & (NREP - 1)) * 128;
        atomicAdd(&rep[lane], S);
        atomicAdd(&rep[64 + lane], Q);
    }
}

// ---------------- GEMM 64x64 (replica-fold BN + relu fused; f16 in, f16 out) ----------

#define G64_ROWS 128
__global__ void gemm64_kernel(const _Float16* __restrict__ hin, const float* __restrict__ W,
                              const float* __restrict__ statsRep, const float* __restrict__ gamma,
                              const float* __restrict__ beta, const float* __restrict__ dis,
                              _Float16* __restrict__ hout) {
    __shared__ float Ws[HID * HID];              // [k][f], f contiguous
    __shared__ float hs[G64_ROWS][HID + 2];      // +2 pad: conflict-free float2 reads
    __shared__ float scb[64], shb[64];
    int t = threadIdx.x;
    int fg = t & 15;
    int rg = t >> 4;
    int base = blockIdx.x * G64_ROWS;

    if (t < 64) bn_coef_rep(statsRep, gamma, beta, t, scb[t], shb[t]);
    {
        const float4* W4 = (const float4*)W;
        float4* Ws4 = (float4*)Ws;
        for (int i = t; i < HID * HID / 4; i += 256) Ws4[i] = W4[i];
    }
    __syncthreads();
    {
        const half4* hin4 = (const half4*)hin;
        for (int i = t; i < G64_ROWS * 16; i += 256) {
            int r = i >> 4, c = i & 15;
            int n = base + r;
            float4 v = make_float4(0.f, 0.f, 0.f, 0.f);
            if (n < N_NODES) {
                half4 h = hin4[n * 16 + c];
                v.x = fmaxf((float)h.x * scb[c * 4 + 0] + shb[c * 4 + 0], 0.f);
                v.y = fmaxf((float)h.y * scb[c * 4 + 1] + shb[c * 4 + 1], 0.f);
                v.z = fmaxf((float)h.z * scb[c * 4 + 2] + shb[c * 4 + 2], 0.f);
                v.w = fmaxf((float)h.w * scb[c * 4 + 3] + shb[c * 4 + 3], 0.f);
            }
            hs[r][c * 4 + 0] = v.x;
            hs[r][c * 4 + 1] = v.y;
            hs[r][c * 4 + 2] = v.z;
            hs[r][c * 4 + 3] = v.w;
        }
    }
    __syncthreads();

    float4 acc[8];
#pragma unroll
    for (int r = 0; r < 8; r++) acc[r] = make_float4(0.f, 0.f, 0.f, 0.f);
    const float4* Ws4 = (const float4*)Ws;
    for (int k = 0; k < HID; k += 2) {
        float4 wk0 = Ws4[k * 16 + fg];
        float4 wk1 = Ws4[(k + 1) * 16 + fg];
#pragma unroll
        for (int r = 0; r < 8; r++) {
            float2 h2 = *(const float2*)&hs[rg * 8 + r][k];
            acc[r].x += h2.x * wk0.x + h2.y * wk1.x;
            acc[r].y += h2.x * wk0.y + h2.y * wk1.y;
            acc[r].z += h2.x * wk0.z + h2.y * wk1.z;
            acc[r].w += h2.x * wk0.w + h2.y * wk1.w;
        }
    }
    half4* hout4 = (half4*)hout;
#pragma unroll
    for (int r = 0; r < 8; r++) {
        int n = base + rg * 8 + r;
        if (n < N_NODES) {
            float dsc = dis[n];
            half4 o;
            o.x = (_Float16)(acc[r].x * dsc);
            o.y = (_Float16)(acc[r].y * dsc);
            o.z = (_Float16)(acc[r].z * dsc);
            o.w = (_Float16)(acc[r].w * dsc);
            hout4[n * 16 + fg] = o;
        }
    }
}

// ---------------- Aggregation 64-dim: 2 nodes/wave (4 slots x 8 half8-cols), f16 y -----

__global__ void aggregate_kernel(const half8* __restrict__ hwh, const int* __restrict__ csrOff,
                                 const int* __restrict__ csrSrc, const float* __restrict__ dis,
                                 const float* __restrict__ bias, half8* __restrict__ y8,
                                 float* __restrict__ statsRep) {
    const int lane = threadIdx.x & 63;
    const int wid = threadIdx.x >> 6;
    const int g = lane >> 5;  // node subgroup 0..1
    const int s = lane & 31;
    const int c = s & 7;      // half8 column within the 64-half row
    const int o = s >> 3;     // edge slot 0..3
    const int wave = blockIdx.x * 4 + wid;
    const int nwaves = gridDim.x * 4;

    const float4 bv0 = ((const float4*)bias)[c * 2];
    const float4 bv1 = ((const float4*)bias)[c * 2 + 1];
    float sa[8], qa[8];
#pragma unroll
    for (int j = 0; j < 8; j++) { sa[j] = 0.f; qa[j] = 0.f; }

    for (int n0 = wave * 2; n0 < N_NODES; n0 += nwaves * 2) {
        int n = n0 + g;
        bool vn = (n < N_NODES);
        int beg = 0, end = 0;
        if (vn) { beg = csrOff[n]; end = csrOff[n + 1]; }
        float acc[8];
#pragma unroll
        for (int j = 0; j < 8; j++) acc[j] = 0.f;
        int e = beg + o;
        int i0 = (e < end) ? csrSrc[e] : N_NODES;
        int i1 = (e + 4 < end) ? csrSrc[e + 4] : N_NODES;
        while (e < end) {
            int j0 = i0, j1 = i1;
            e += 8;
            i0 = (e < end) ? csrSrc[e] : N_NODES;
            i1 = (e + 4 < end) ? csrSrc[e + 4] : N_NODES;
            half8 h0 = hwh[(size_t)j0 * 8 + c];
            half8 h1 = hwh[(size_t)j1 * 8 + c];
#pragma unroll
            for (int j = 0; j < 8; j++) acc[j] += (float)h0[j] + (float)h1[j];
        }
#pragma unroll
        for (int j = 0; j < 8; j++) {
            acc[j] += __shfl_xor(acc[j], 8, 64);
            acc[j] += __shfl_xor(acc[j], 16, 64);
        }
        if (o == 0 && vn) {
            float d = dis[n];
            float val[8];
            val[0] = acc[0] * d + bv0.x; val[1] = acc[1] * d + bv0.y;
            val[2] = acc[2] * d + bv0.z; val[3] = acc[3] * d + bv0.w;
            val[4] = acc[4] * d + bv1.x; val[5] = acc[5] * d + bv1.y;
            val[6] = acc[6] * d + bv1.z; val[7] = acc[7] * d + bv1.w;
            half8 ov;
#pragma unroll
            for (int j = 0; j < 8; j++) ov[j] = (_Float16)val[j];
            y8[(size_t)n * 8 + c] = ov;
#pragma unroll
            for (int j = 0; j < 8; j++) { sa[j] += val[j]; qa[j] += val[j] * val[j]; }
        }
    }
#pragma unroll
    for (int j = 0; j < 8; j++) {
        sa[j] += __shfl_xor(sa[j], 32, 64);
        qa[j] += __shfl_xor(qa[j], 32, 64);
    }
    __shared__ float ls[4][64], lq[4][64];
    ls[wid][lane] = 0.f;
    lq[wid][lane] = 0.f;
    if (lane < 8) {  // o==0 && g==0; c == lane
#pragma unroll
        for (int j = 0; j < 8; j++) { ls[wid][lane * 8 + j] = sa[j]; lq[wid][lane * 8 + j] = qa[j]; }
    }
    __syncthreads();
    if (wid == 0) {
        float S = ls[0][lane] + ls[1][lane] + ls[2][lane] + ls[3][lane];
        float Q = lq[0][lane] + lq[1][lane] + lq[2][lane] + lq[3][lane];
        float* rep = statsRep + (blockIdx.x & (NREP - 1)) * 128;
        atomicAdd(&rep[lane], S);
        atomicAdd(&rep[64 + lane], Q);
    }
}

// ---------------- Pool (replica-fold BN + relu fused) + head ----------------

#define POOL_CHUNK 256
__global__ void pool_kernel(const _Float16* __restrict__ y, const int* __restrict__ batch,
                            const float* __restrict__ statsRep, const float* __restrict__ gamma,
                            const float* __restrict__ beta, float* __restrict__ pool,
                            float* __restrict__ cnt) {
    __shared__ float scs[64], shs[64];
    int t = threadIdx.x;
    int f = t & 63;
    int nl = t >> 6;
    if (t < 64) bn_coef_rep(statsRep, gamma, beta, t, scs[t], shs[t]);
    __syncthreads();
    float sc = scs[f], sh = shs[f];
    int base = blockIdx.x * POOL_CHUNK;
    int endn = min(base + POOL_CHUNK, N_NODES);
    int g_cur = -1;
    float acc = 0.f;
    float c_acc = 0.f;
    for (int n = base + nl; n < endn; n += 4) {
        int g = batch[n];
        float v = fmaxf((float)y[(size_t)n * HID + f] * sc + sh, 0.f);
        if (g != g_cur) {
            if (g_cur >= 0) {
                atomicAdd(&pool[g_cur * HID + f], acc);
                if (f == 0) atomicAdd(&cnt[g_cur], c_acc);
            }
            g_cur = g;
            acc = 0.f;
            c_acc = 0.f;
        }
        acc += v;
        c_acc += 1.f;
    }
    if (g_cur >= 0) {
        atomicAdd(&pool[g_cur * HID + f], acc);
        if (f == 0) atomicAdd(&cnt[g_cur], c_acc);
    }
}

__global__ void head_kernel(const float* __restrict__ pool, const float* __restrict__ cnt,
                            const float* __restrict__ Wc1, const float* __restrict__ bc1,
                            const float* __restrict__ Wc2, const float* __restrict__ bc2,
                            float* __restrict__ out) {
    int g = blockIdx.x;
    int f = threadIdx.x;  // 64 threads
    __shared__ float p[64], z[64];
    float c = fmaxf(cnt[g], 1.0f);
    p[f] = pool[g * HID + f] / c;
    __syncthreads();
    float acc = bc1[f];
    for (int k = 0; k < 64; k++) acc += p[k] * Wc1[k * 64 + f];
    z[f] = fmaxf(acc, 0.f);
    __syncthreads();
    if (f < 2) {
        float o = bc2[f];
        for (int k = 0; k < 64; k++) o += z[k] * Wc2[k * 2 + f];
        out[g * 2 + f] = o;
    }
}

// ---------------- launch ----------------

extern "C" void kernel_launch(void* const* d_in, const int* in_sizes, int n_in,
                              void* d_out, int out_size, void* d_ws, size_t ws_size,
                              hipStream_t stream) {
    const float* x      = (const float*)d_in[0];
    const int*   ei     = (const int*)d_in[1];
    const int*   batch  = (const int*)d_in[2];
    const float* bn_in_g = (const float*)d_in[3];
    const float* bn_in_b = (const float*)d_in[4];
    const float* W0 = (const float*)d_in[5];
    const float* b0 = (const float*)d_in[6];
    const float* g0 = (const float*)d_in[7];
    const float* be0 = (const float*)d_in[8];
    const float* W1 = (const float*)d_in[9];
    const float* b1 = (const float*)d_in[10];
    const float* g1 = (const float*)d_in[11];
    const float* be1 = (const float*)d_in[12];
    const float* W2 = (const float*)d_in[13];
    const float* b2 = (const float*)d_in[14];
    const float* g2 = (const float*)d_in[15];
    const float* be2 = (const float*)d_in[16];
    const float* Wc1 = (const float*)d_in[17];
    const float* bc1 = (const float*)d_in[18];
    const float* Wc2 = (const float*)d_in[19];
    const float* bc2 = (const float*)d_in[20];
    float* out = (float*)d_out;

    char* w = (char*)d_ws;
    size_t off = 0;
    auto take = [&](size_t bytes) {
        size_t r = off;
        off += (bytes + 255) & ~(size_t)255;
        return r;
    };
    // ---- zero region (one memset) ----
    float* stats    = (float*)(w + take(256 * 4));             // s0: [sums 64][sumsq 64]
    float* statsRep = (float*)(w + take(3 * NREP * 128 * 4));  // replicated accumulators
    float* pool     = (float*)(w + take((size_t)N_GRAPHS * HID * 4));
    float* cnt      = (float*)(w + take((size_t)N_GRAPHS * 4));
    int* bucketCnt  = (int*)(w + take((size_t)NB_BUCKETS * 4));
    size_t zero_end = off;
    // ---- rest ----
    float* dis    = (float*)(w + take((size_t)N_NODES * 4));
    int* csrOff   = (int*)(w + take((size_t)(N_NODES + 1) * 4));
    int* csrSrc   = (int*)(w + take((size_t)(CSR_LEN + 64) * 4));
    _Float16* hwBuf = (_Float16*)(w + take((size_t)(N_NODES + 1) * HID * 2));  // f16 msgs +dummy
    _Float16* yBuf  = (_Float16*)(w + take((size_t)N_NODES * HID * 2));        // f16 activations
    _Float16* msgBuf = (_Float16*)(w + take((size_t)(N_NODES + 1) * IN_DIM * 2));  // f16 16-dim
    int* regions  = (int*)hwBuf;   // alias: consumed by build_kernel before gemm64 writes
    (void)ws_size; (void)n_in; (void)in_sizes; (void)out_size;

    hipMemsetAsync(w, 0, zero_end, stream);

    const int nbBin   = (N_EDGES + BIN_TILE - 1) / BIN_TILE;  // 293
    const int nbPre   = ((N_NODES + 1) * 4 + 255) / 256;
    const int nbG64   = (N_NODES + G64_ROWS - 1) / G64_ROWS;
    const int nbAgg16 = (N_NODES + 16 * 4 - 1) / (16 * 4);  // 4 waves x 4 nodes per block
    const int nbAgg64 = (N_NODES + 8 * 4 - 1) / (8 * 4);    // 4 waves x 2 nodes per block

    // CSR build (bucketed; self-loops folded in)
    bin_kernel<<<nbBin, 256, 0, stream>>>(ei, bucketCnt, regions);
    build_kernel<<<NB_BUCKETS, 256, 0, stream>>>(regions, bucketCnt, csrOff, csrSrc, dis);

    float* s0 = stats;
    float* rep1 = statsRep + 0 * NREP * 128;
    float* rep2 = statsRep + 1 * NREP * 128;
    float* rep3 = statsRep + 2 * NREP * 128;

    // input BN stats (also zeroes hwBuf f16 dummy row)
    stats_x<<<256, 256, 0, stream>>>(x, s0, s0 + 64, hwBuf);

    // layer 0: premsg (f16) -> fused 16-dim aggregate + W0 GEMM (f16 y out)
    premsg_kernel<<<nbPre, 256, 0, stream>>>(x, s0, s0 + 64, bn_in_g, bn_in_b, dis,
                                             (half4*)msgBuf);
    agg16_gemm0_kernel<<<nbAgg16, 256, 0, stream>>>((const half4*)msgBuf, csrOff, csrSrc, dis,
                                                    W0, b0, yBuf, rep1);

    // layer 1 (gemm folds rep1 reduce + BN)
    gemm64_kernel<<<nbG64, 256, 0, stream>>>(yBuf, W1, rep1, g0, be0, dis, hwBuf);
    aggregate_kernel<<<nbAgg64, 256, 0, stream>>>((const half8*)hwBuf, csrOff, csrSrc, dis, b1,
                                                  (half8*)yBuf, rep2);
    // layer 2
    gemm64_kernel<<<nbG64, 256, 0, stream>>>(yBuf, W2, rep2, g1, be1, dis, hwBuf);
    aggregate_kernel<<<nbAgg64, 256, 0, stream>>>((const half8*)hwBuf, csrOff, csrSrc, dis, b2,
                                                  (half8*)yBuf, rep3);

    // pool (folds rep3 reduce + BN) + head
    const int nbPool = (N_NODES + POOL_CHUNK - 1) / POOL_CHUNK;
    pool_kernel<<<nbPool, 256, 0, stream>>>(yBuf, batch, rep3, g2, be2, pool, cnt);
    head_kernel<<<N_GRAPHS, 64, 0, stream>>>(pool, cnt, Wc1, bc1, Wc2, bc2, out);
}